// Round 3
// baseline (2995.962 us; speedup 1.0000x reference)
//
#include <hip/hip_runtime.h>
#include <hip/hip_bf16.h>

// B=1024, L=100, D=512, 2 layers. Outputs: x'[B,L,D] f32 then seq_emb[B,D] f32.
#define B_ 1024
#define L_ 100
#define D_ 512
#define LP 128                    // padded L for MFMA tiles
#define ROWS (B_*L_)              // 102400
#define XELEMS ((size_t)ROWS*D_)  // 52428800
#define HB 512                    // batches per half
#define HR (HB*L_)                // rows per half = 51200
#define CATW 1536                 // cat row stride: [msg(512) | xbf16(512) | xr(512)]

typedef __attribute__((ext_vector_type(8))) short short8;
typedef __attribute__((ext_vector_type(4))) float f32x4;

__device__ __forceinline__ short f2bf(float f) {
    __hip_bfloat16 h = __float2bfloat16(f);
    return *reinterpret_cast<short*>(&h);
}

__device__ __forceinline__ void cp16(void* lds, const void* g) {
    __builtin_amdgcn_global_load_lds(
        (const __attribute__((address_space(1))) unsigned int*)g,
        (__attribute__((address_space(3))) unsigned int*)lds, 16, 0, 0);
}

__device__ __forceinline__ f32x4 mfma16(short8 a, short8 b, f32x4 c) {
    return __builtin_amdgcn_mfma_f32_16x16x32_bf16(a, b, c, 0, 0, 0);
}

// ---------------- positional encoding ----------------
__global__ __launch_bounds__(256) void pe_kernel(float* __restrict__ pe) {
    int idx = blockIdx.x * 256 + threadIdx.x;
    if (idx >= L_ * D_) return;
    int l = idx >> 9;
    int d = idx & 511;
    int i = d >> 1;
    float div = __expf((float)(2 * i) * (-9.210340371976184f / 512.0f));
    float angle = (float)l * div;
    pe[idx] = (d & 1) ? __cosf(angle) : __sinf(angle);
}

// ---------------- weight transpose+cvt: W[k][n] f32 -> Wt[n][k] bf16 ----------------
__global__ __launch_bounds__(256) void cvtw_kernel(const float* __restrict__ W,
                                                   __hip_bfloat16* __restrict__ Wt) {
    int idx = blockIdx.x * 256 + threadIdx.x;   // over 512*1024
    int n = idx >> 10, k = idx & 1023;
    Wt[idx] = __float2bfloat16(W[(size_t)k * D_ + n]);
}

// ---- per-batch transpose + cat x-copy: x[b][l][d] f32 -> xT[bl][d][lp128] bf16,
//      and cat[row][512+d] = bf16(x) ----
__global__ __launch_bounds__(256) void prep_xt_kernel(const float* __restrict__ x,
                                                      __hip_bfloat16* __restrict__ xTb,
                                                      __hip_bfloat16* __restrict__ cat,
                                                      int bh) {
    const int bl = blockIdx.y;            // local batch 0..511
    const int b = bh * HB + bl;
    const int d0 = blockIdx.x * 64;
    __shared__ __hip_bfloat16 t[64][66];
    const float* xb = x + (size_t)b * L_ * D_;
    const int tid = threadIdx.x;
    for (int l0 = 0; l0 < LP; l0 += 64) {
        int l_loc = tid >> 2;
        int dq = tid & 3;
        int l = l0 + l_loc;
        #pragma unroll
        for (int i = 0; i < 4; ++i) {
            int d_loc = (dq * 4 + i) * 4;
            float4 v = (l < L_) ? *(const float4*)(xb + (size_t)l * D_ + d0 + d_loc)
                                : make_float4(0.f, 0.f, 0.f, 0.f);
            short s0 = f2bf(v.x), s1 = f2bf(v.y), s2 = f2bf(v.z), s3 = f2bf(v.w);
            t[l_loc][d_loc + 0] = *reinterpret_cast<__hip_bfloat16*>(&s0);
            t[l_loc][d_loc + 1] = *reinterpret_cast<__hip_bfloat16*>(&s1);
            t[l_loc][d_loc + 2] = *reinterpret_cast<__hip_bfloat16*>(&s2);
            t[l_loc][d_loc + 3] = *reinterpret_cast<__hip_bfloat16*>(&s3);
            if (l < L_) {
                union { short s[4]; unsigned long long u; } pk;
                pk.s[0] = s0; pk.s[1] = s1; pk.s[2] = s2; pk.s[3] = s3;
                *(unsigned long long*)(cat + ((size_t)bl * L_ + l) * CATW + 512 + d0 + d_loc) = pk.u;
            }
        }
        __syncthreads();
        int dl = tid >> 2, seg = tid & 3;
        short8 lo, hi;
        #pragma unroll
        for (int j = 0; j < 8; ++j) {
            __hip_bfloat16 a = t[seg * 16 + j][dl];
            __hip_bfloat16 bswap = t[seg * 16 + 8 + j][dl];
            lo[j] = *reinterpret_cast<short*>(&a);
            hi[j] = *reinterpret_cast<short*>(&bswap);
        }
        __hip_bfloat16* dst = xTb + ((size_t)bl * D_ + d0 + dl) * LP + l0 + seg * 16;
        *(short8*)dst = lo;
        *(short8*)(dst + 8) = hi;
        __syncthreads();
    }
}

// ---------------- fused attention: block per batch, 4 waves, MFMA ----------------
__global__ __launch_bounds__(256) void attn_kernel(
    const float* __restrict__ x, const float* __restrict__ pe,
    const int* __restrict__ text_len, const __hip_bfloat16* __restrict__ xTb,
    __hip_bfloat16* __restrict__ cat, int bh)
{
    __shared__ __align__(16) char sm[16384 + 32768];
    char* XP = sm;             // [128][64] bf16, swizzled, rowbytes=128
    char* P  = sm + 16384;     // [128][128] bf16, swizzled, rowbytes=256
    const int bl = blockIdx.x;
    const int b = bh * HB + bl;
    const int len = text_len[b];
    const int tid = threadIdx.x;
    const int w = tid >> 6, g = (tid >> 4) & 3, cl = tid & 15;
    const float* xb = x + (size_t)b * L_ * D_;

    f32x4 accS[2][8];
    const f32x4 fz = {0.f, 0.f, 0.f, 0.f};
    #pragma unroll
    for (int i = 0; i < 2; ++i)
        #pragma unroll
        for (int j = 0; j < 8; ++j) accS[i][j] = fz;

    // ---- phase A: S = xp @ xp^T ----
    for (int kc = 0; kc < D_; kc += 64) {
        #pragma unroll
        for (int i = 0; i < 4; ++i) {
            int c = tid + 256 * i;
            int row = c >> 3, k8d = c & 7;
            int k = kc + 8 * (k8d ^ (row & 7));
            short8 h;
            if (row < L_) {
                const float* px = xb + (size_t)row * D_ + k;
                const float* pp = pe + row * D_ + k;
                float4 a0 = *(const float4*)px, a1 = *(const float4*)(px + 4);
                float4 b0 = *(const float4*)pp, b1 = *(const float4*)(pp + 4);
                h[0] = f2bf(a0.x + b0.x); h[1] = f2bf(a0.y + b0.y);
                h[2] = f2bf(a0.z + b0.z); h[3] = f2bf(a0.w + b0.w);
                h[4] = f2bf(a1.x + b1.x); h[5] = f2bf(a1.y + b1.y);
                h[6] = f2bf(a1.z + b1.z); h[7] = f2bf(a1.w + b1.w);
            } else {
                #pragma unroll
                for (int q = 0; q < 8; ++q) h[q] = 0;
            }
            *(short8*)(XP + row * 128 + 16 * k8d) = h;
        }
        __syncthreads();
        #pragma unroll
        for (int kt = 0; kt < 2; ++kt) {
            short8 a[2];
            #pragma unroll
            for (int rt = 0; rt < 2; ++rt) {
                int r = 32 * w + 16 * rt + cl;
                a[rt] = *(const short8*)(XP + r * 128 + ((16 * g + 64 * kt) ^ ((r & 7) << 4)));
            }
            #pragma unroll
            for (int ct = 0; ct < 8; ++ct) {
                int m = 16 * ct + cl;
                short8 bb = *(const short8*)(XP + m * 128 + ((16 * g + 64 * kt) ^ ((m & 7) << 4)));
                accS[0][ct] = mfma16(a[0], bb, accS[0][ct]);
                accS[1][ct] = mfma16(a[1], bb, accS[1][ct]);
            }
        }
        __syncthreads();
    }

    // ---- phase B: masked softmax (reference MASK_FILL=1e-10, pads excluded) ----
    #pragma unroll
    for (int rt = 0; rt < 2; ++rt) {
        #pragma unroll
        for (int reg = 0; reg < 4; ++reg) {
            int rl = 32 * w + 16 * rt + 4 * g + reg;
            float s[8];
            #pragma unroll
            for (int ct = 0; ct < 8; ++ct) {
                int col = 16 * ct + cl;
                float v = accS[rt][ct][reg];
                if (col >= L_) v = -INFINITY;                  // padding: excluded
                else if (rl >= len || col >= len) v = 1e-10f;  // MASK_FILL
                s[ct] = v;
            }
            float mx = s[0];
            #pragma unroll
            for (int ct = 1; ct < 8; ++ct) mx = fmaxf(mx, s[ct]);
            mx = fmaxf(mx, __shfl_xor(mx, 1));
            mx = fmaxf(mx, __shfl_xor(mx, 2));
            mx = fmaxf(mx, __shfl_xor(mx, 4));
            mx = fmaxf(mx, __shfl_xor(mx, 8));
            float e[8], sum = 0.f;
            #pragma unroll
            for (int ct = 0; ct < 8; ++ct) { e[ct] = __expf(s[ct] - mx); sum += e[ct]; }
            sum += __shfl_xor(sum, 1);
            sum += __shfl_xor(sum, 2);
            sum += __shfl_xor(sum, 4);
            sum += __shfl_xor(sum, 8);
            float inv = 1.f / sum;
            #pragma unroll
            for (int ct = 0; ct < 8; ++ct) {
                int col = 16 * ct + cl;
                *(short*)(P + rl * 256 + ((col * 2) ^ ((rl & 7) << 4))) = f2bf(e[ct] * inv);
            }
        }
    }
    // P rows [32w,32w+32) are written and read only by wave w: no barrier needed.

    // ---- phase C: message = P @ x -> cat[:,0:512] ----
    const __hip_bfloat16* xT = xTb + (size_t)bl * D_ * LP;
    for (int nc = 0; nc < 4; ++nc) {
        f32x4 accM[2][8];
        #pragma unroll
        for (int i = 0; i < 2; ++i)
            #pragma unroll
            for (int j = 0; j < 8; ++j) accM[i][j] = fz;
        #pragma unroll
        for (int kt = 0; kt < 4; ++kt) {
            short8 a[2];
            #pragma unroll
            for (int rt = 0; rt < 2; ++rt) {
                int r = 32 * w + 16 * rt + cl;
                a[rt] = *(const short8*)(P + r * 256 + ((16 * g + 64 * kt) ^ ((r & 7) << 4)));
            }
            #pragma unroll
            for (int nt = 0; nt < 8; ++nt) {
                int d = nc * 128 + nt * 16 + cl;
                short8 bb = *(const short8*)(xT + (size_t)d * LP + 8 * g + 32 * kt);
                accM[0][nt] = mfma16(a[0], bb, accM[0][nt]);
                accM[1][nt] = mfma16(a[1], bb, accM[1][nt]);
            }
        }
        #pragma unroll
        for (int rt = 0; rt < 2; ++rt) {
            #pragma unroll
            for (int nt = 0; nt < 8; ++nt) {
                #pragma unroll
                for (int reg = 0; reg < 4; ++reg) {
                    int rl = 32 * w + 16 * rt + 4 * g + reg;
                    if (rl < L_) {
                        int d = nc * 128 + nt * 16 + cl;
                        cat[((size_t)bl * L_ + rl) * CATW + d] = __float2bfloat16(accM[rt][nt][reg]);
                    }
                }
            }
        }
    }
}

// ---------------- 256x256 BK=64 8-wave counted-vmcnt GEMM for gates ----------------
// MODE 0: N=1024, B=Wur^T, A = cat[:,0:1024]; epilogue sigmoid -> upd / xr.
// MODE 1: N=512,  B=Wo^T,  A = cat cols {0:512, 1024:1536}; epilogue GRU combine.
template<int MODE>
__global__ __launch_bounds__(512, 1) void gemm_gates(
    const __hip_bfloat16* __restrict__ cat,
    const __hip_bfloat16* __restrict__ Wt,
    const float* __restrict__ bias0, const float* __restrict__ bias1,
    const float* __restrict__ xsrc,         // f32 x rows (half-local base)
    __hip_bfloat16* __restrict__ upd,       // MODE0: write; MODE1: read
    __hip_bfloat16* __restrict__ catw,      // MODE0: xr writes into cat[:,1024:]
    float* __restrict__ xdst)               // MODE1: x output (half-local base)
{
    __shared__ __align__(16) char sm[131072];
    const int tid = threadIdx.x;
    const int lane = tid & 63;
    const int wid = tid >> 6;
    const int wr = wid >> 2, wc = wid & 3;
    const int g = lane >> 4, cl = lane & 15;
    constexpr int NY = (MODE == 0) ? 4 : 2;
    const int cpx = gridDim.x >> 3;
    const int bid = blockIdx.x;
    const int swz = (bid & 7) * cpx + (bid >> 3);   // bijective: grid % 8 == 0
    const int bx = swz / NY, by = swz % NY;
    const size_t R0 = (size_t)bx * 256;
    const int col0 = by * 256;

    // staging source geometry (constant per thread)
    int srow[4], soff[4];
    #pragma unroll
    for (int i = 0; i < 4; ++i) {
        int c = tid + 512 * i;
        int row = c >> 3, k8 = c & 7;
        srow[i] = row;
        soff[i] = 8 * (k8 ^ (row & 7));
    }

    auto stage = [&](int tile, char* buf) {
        const int kc = tile * 64;
        const int kb = (MODE == 0) ? kc : (kc < 512 ? kc : kc + 512);
        char* Ab = buf;
        char* Bb = buf + 32768;
        #pragma unroll
        for (int i = 0; i < 4; ++i) {
            int c = tid + 512 * i;
            cp16(Ab + c * 16, cat + (R0 + srow[i]) * CATW + kb + soff[i]);
        }
        #pragma unroll
        for (int i = 0; i < 4; ++i) {
            int c = tid + 512 * i;
            cp16(Bb + c * 16, Wt + (size_t)(col0 + srow[i]) * 1024 + kc + soff[i]);
        }
    };

    f32x4 acc[8][4];
    const f32x4 fz = {0.f, 0.f, 0.f, 0.f};
    #pragma unroll
    for (int i = 0; i < 8; ++i)
        #pragma unroll
        for (int j = 0; j < 4; ++j) acc[i][j] = fz;

    // prologue: stage tiles 0,1
    stage(0, sm);
    stage(1, sm + 65536);
    asm volatile("s_waitcnt vmcnt(8)" ::: "memory");
    __builtin_amdgcn_sched_barrier(0);
    __builtin_amdgcn_s_barrier();

    short8 aA[4][2], bA[2][2], bB[2][2];

    #pragma unroll 1
    for (int t = 0; t < 16; ++t) {
        char* Ab = sm + ((t & 1) << 16);
        char* Bb = Ab + 32768;

        // ---- P0: A rt0-3, B ct0-1; MFMA quad (rt0-3 x ct0-1) ----
        #pragma unroll
        for (int rt = 0; rt < 4; ++rt) {
            int r = wr * 128 + rt * 16 + cl;
            #pragma unroll
            for (int kt = 0; kt < 2; ++kt)
                aA[rt][kt] = *(const short8*)(Ab + r * 128 + (((kt * 4 + g) ^ (r & 7)) << 4));
        }
        #pragma unroll
        for (int ct = 0; ct < 2; ++ct) {
            int n = wc * 64 + ct * 16 + cl;
            #pragma unroll
            for (int kt = 0; kt < 2; ++kt)
                bA[ct][kt] = *(const short8*)(Bb + n * 128 + (((kt * 4 + g) ^ (n & 7)) << 4));
        }
        __builtin_amdgcn_s_setprio(1);
        #pragma unroll
        for (int rt = 0; rt < 4; ++rt)
            #pragma unroll
            for (int ct = 0; ct < 2; ++ct)
                #pragma unroll
                for (int kt = 0; kt < 2; ++kt)
                    acc[rt][ct] = mfma16(aA[rt][kt], bA[ct][kt], acc[rt][ct]);
        __builtin_amdgcn_s_setprio(0);

        // ---- P1: B ct2-3; MFMA quad (rt0-3 x ct2-3) ----
        #pragma unroll
        for (int ct = 0; ct < 2; ++ct) {
            int n = wc * 64 + (ct + 2) * 16 + cl;
            #pragma unroll
            for (int kt = 0; kt < 2; ++kt)
                bB[ct][kt] = *(const short8*)(Bb + n * 128 + (((kt * 4 + g) ^ (n & 7)) << 4));
        }
        __builtin_amdgcn_s_setprio(1);
        #pragma unroll
        for (int rt = 0; rt < 4; ++rt)
            #pragma unroll
            for (int ct = 0; ct < 2; ++ct)
                #pragma unroll
                for (int kt = 0; kt < 2; ++kt)
                    acc[rt][ct + 2] = mfma16(aA[rt][kt], bB[ct][kt], acc[rt][ct + 2]);
        __builtin_amdgcn_s_setprio(0);

        // ---- P2: A rt4-7; MFMA quad (rt4-7 x ct0-1) ----
        #pragma unroll
        for (int rt = 0; rt < 4; ++rt) {
            int r = wr * 128 + (rt + 4) * 16 + cl;
            #pragma unroll
            for (int kt = 0; kt < 2; ++kt)
                aA[rt][kt] = *(const short8*)(Ab + r * 128 + (((kt * 4 + g) ^ (r & 7)) << 4));
        }
        __builtin_amdgcn_s_setprio(1);
        #pragma unroll
        for (int rt = 0; rt < 4; ++rt)
            #pragma unroll
            for (int ct = 0; ct < 2; ++ct)
                #pragma unroll
                for (int kt = 0; kt < 2; ++kt)
                    acc[rt + 4][ct] = mfma16(aA[rt][kt], bA[ct][kt], acc[rt + 4][ct]);
        __builtin_amdgcn_s_setprio(0);

        // all LDS reads of this buffer are consumed; sync before overwriting
        asm volatile("s_waitcnt lgkmcnt(0)" ::: "memory");
        __builtin_amdgcn_sched_barrier(0);
        __builtin_amdgcn_s_barrier();

        // ---- P3: stage tile t+2 into this buffer; MFMA quad (rt4-7 x ct2-3) ----
        if (t < 14) stage(t + 2, Ab);
        __builtin_amdgcn_s_setprio(1);
        #pragma unroll
        for (int rt = 0; rt < 4; ++rt)
            #pragma unroll
            for (int ct = 0; ct < 2; ++ct)
                #pragma unroll
                for (int kt = 0; kt < 2; ++kt)
                    acc[rt + 4][ct + 2] = mfma16(aA[rt][kt], bB[ct][kt], acc[rt + 4][ct + 2]);
        __builtin_amdgcn_s_setprio(0);

        if (t < 15) {
            if (t < 14) asm volatile("s_waitcnt vmcnt(8)" ::: "memory");
            else        asm volatile("s_waitcnt vmcnt(0)" ::: "memory");
            __builtin_amdgcn_sched_barrier(0);
            __builtin_amdgcn_s_barrier();
        }
    }

    // ---- epilogue ----
    if (MODE == 0) {
        const bool isU = (col0 < 512);
        #pragma unroll
        for (int ct = 0; ct < 4; ++ct) {
            int colg = col0 + wc * 64 + ct * 16 + cl;
            float bb = isU ? bias0[colg] : bias1[colg - 512];
            #pragma unroll
            for (int rt = 0; rt < 8; ++rt) {
                #pragma unroll
                for (int reg = 0; reg < 4; ++reg) {
                    size_t grow = R0 + wr * 128 + rt * 16 + g * 4 + reg;
                    float v = 1.f / (1.f + __expf(-(acc[rt][ct][reg] + bb)));
                    if (isU) {
                        upd[grow * D_ + colg] = __float2bfloat16(v);
                    } else {
                        int c2 = colg - 512;
                        float xv = xsrc[grow * D_ + c2];
                        catw[grow * CATW + 1024 + c2] = __float2bfloat16(xv * v);
                    }
                }
            }
        }
    } else {
        #pragma unroll
        for (int ct = 0; ct < 4; ++ct) {
            int colg = col0 + wc * 64 + ct * 16 + cl;
            float bb = bias0[colg];
            #pragma unroll
            for (int rt = 0; rt < 8; ++rt) {
                #pragma unroll
                for (int reg = 0; reg < 4; ++reg) {
                    size_t grow = R0 + wr * 128 + rt * 16 + g * 4 + reg;
                    float cand = tanhf(acc[rt][ct][reg] + bb);
                    float u = __bfloat162float(upd[grow * D_ + colg]);
                    float xv = xsrc[grow * D_ + colg];
                    xdst[grow * D_ + colg] = xv + u * (cand - xv);
                }
            }
        }
    }
}

// ---------------- masked mean pooling ----------------
__global__ __launch_bounds__(256) void pool_kernel(
    const float* __restrict__ x, const int* __restrict__ text_len,
    float* __restrict__ seq)
{
    int b = blockIdx.x;
    int len = text_len[b];
    float invlen = 1.f / (float)len;
    const float* xb = x + (size_t)b * L_ * D_;
    for (int d = threadIdx.x; d < D_; d += 256) {
        float acc = 0.f;
        for (int l = 0; l < len; ++l)
            acc += xb[(size_t)l * D_ + d];
        seq[(size_t)b * D_ + d] = acc * invlen;
    }
}

extern "C" void kernel_launch(void* const* d_in, const int* in_sizes, int n_in,
                              void* d_out, int out_size, void* d_ws, size_t ws_size,
                              hipStream_t stream) {
    const float* x_in = (const float*)d_in[0];
    const int* text_len = (const int*)d_in[1];
    const float* W_r = (const float*)d_in[2];
    const float* b_r = (const float*)d_in[3];
    const float* W_u = (const float*)d_in[4];
    const float* b_u = (const float*)d_in[5];
    const float* W_o = (const float*)d_in[6];
    const float* b_o = (const float*)d_in[7];

    float* xwork = (float*)d_out;
    float* seq_out = (float*)d_out + XELEMS;

    char* ws = (char*)d_ws;
    float* pe            = (float*)ws;                         // 204800 B
    __hip_bfloat16* WurT = (__hip_bfloat16*)(ws + 204800);     // [1024][1024] bf16 (u rows 0-511, r rows 512-1023)
    __hip_bfloat16* WoT  = (__hip_bfloat16*)(ws + 2301952);    // [512][1024] bf16
    __hip_bfloat16* cat  = (__hip_bfloat16*)(ws + 3350528);    // [51200][1536] bf16
    char* unionR         = ws + 160636928ull;                  // 67108864 B
    __hip_bfloat16* xTb  = (__hip_bfloat16*)unionR;            // [512][512][128] bf16
    __hip_bfloat16* upd  = (__hip_bfloat16*)unionR;            // [51200][512] bf16 (aliased; disjoint lifetime)

    pe_kernel<<<(L_ * D_ + 255) / 256, 256, 0, stream>>>(pe);
    cvtw_kernel<<<2048, 256, 0, stream>>>(W_u, WurT);
    cvtw_kernel<<<2048, 256, 0, stream>>>(W_r, WurT + 512 * 1024);
    cvtw_kernel<<<2048, 256, 0, stream>>>(W_o, WoT);

    for (int layer = 0; layer < 2; ++layer) {
        const float* xs = layer ? (const float*)xwork : x_in;
        for (int h = 0; h < 2; ++h) {
            const float* xsh = xs + (size_t)h * HR * D_;
            float* xdh = xwork + (size_t)h * HR * D_;
            prep_xt_kernel<<<dim3(8, HB), 256, 0, stream>>>(xs, xTb, cat, h);
            attn_kernel<<<HB, 256, 0, stream>>>(xs, pe, text_len, xTb, cat, h);
            gemm_gates<0><<<800, 512, 0, stream>>>(cat, WurT, b_u, b_r, xsh, upd, cat, nullptr);
            gemm_gates<1><<<400, 512, 0, stream>>>(cat, WoT, b_o, nullptr, xsh, upd, nullptr, xdh);
        }
    }
    pool_kernel<<<B_, 256, 0, stream>>>(xwork, text_len, seq_out);
}

// Round 4
// 2952.459 us; speedup vs baseline: 1.0147x; 1.0147x over previous
//
#include <hip/hip_runtime.h>
#include <hip/hip_bf16.h>

// B=1024, L=100, D=512, 2 layers. Outputs: x'[B,L,D] f32 then seq_emb[B,D] f32.
#define B_ 1024
#define L_ 100
#define D_ 512
#define LP 128                    // padded L for MFMA tiles
#define ROWS (B_*L_)              // 102400
#define XELEMS ((size_t)ROWS*D_)  // 52428800
#define HB 512                    // batches per half
#define HR (HB*L_)                // rows per half = 51200
#define CATW 1536                 // cat row stride: [msg(512) | xbf16(512) | xr(512)]

typedef __attribute__((ext_vector_type(8))) short short8;
typedef __attribute__((ext_vector_type(4))) float f32x4;

__device__ __forceinline__ short f2bf(float f) {
    __hip_bfloat16 h = __float2bfloat16(f);
    return *reinterpret_cast<short*>(&h);
}

__device__ __forceinline__ void cp16(void* lds, const void* g) {
    __builtin_amdgcn_global_load_lds(
        (const __attribute__((address_space(1))) unsigned int*)g,
        (__attribute__((address_space(3))) unsigned int*)lds, 16, 0, 0);
}

__device__ __forceinline__ f32x4 mfma16(short8 a, short8 b, f32x4 c) {
    return __builtin_amdgcn_mfma_f32_16x16x32_bf16(a, b, c, 0, 0, 0);
}

// ---------------- positional encoding ----------------
__global__ __launch_bounds__(256) void pe_kernel(float* __restrict__ pe) {
    int idx = blockIdx.x * 256 + threadIdx.x;
    if (idx >= L_ * D_) return;
    int l = idx >> 9;
    int d = idx & 511;
    int i = d >> 1;
    float div = __expf((float)(2 * i) * (-9.210340371976184f / 512.0f));
    float angle = (float)l * div;
    pe[idx] = (d & 1) ? __cosf(angle) : __sinf(angle);
}

// ---------------- weight transpose+cvt: W[k][n] f32 -> Wt[n][k] bf16 ----------------
__global__ __launch_bounds__(256) void cvtw_kernel(const float* __restrict__ W,
                                                   __hip_bfloat16* __restrict__ Wt) {
    int idx = blockIdx.x * 256 + threadIdx.x;   // over 512*1024
    int n = idx >> 10, k = idx & 1023;
    Wt[idx] = __float2bfloat16(W[(size_t)k * D_ + n]);
}

// ---- per-batch transpose + cat x-copy: x[b][l][d] f32 -> xT[bl][d][lp128] bf16,
//      and cat[row][512+d] = bf16(x) ----
__global__ __launch_bounds__(256) void prep_xt_kernel(const float* __restrict__ x,
                                                      __hip_bfloat16* __restrict__ xTb,
                                                      __hip_bfloat16* __restrict__ cat,
                                                      int bh) {
    const int bl = blockIdx.y;            // local batch 0..511
    const int b = bh * HB + bl;
    const int d0 = blockIdx.x * 64;
    __shared__ __hip_bfloat16 t[64][66];
    const float* xb = x + (size_t)b * L_ * D_;
    const int tid = threadIdx.x;
    for (int l0 = 0; l0 < LP; l0 += 64) {
        int l_loc = tid >> 2;
        int dq = tid & 3;
        int l = l0 + l_loc;
        #pragma unroll
        for (int i = 0; i < 4; ++i) {
            int d_loc = (dq * 4 + i) * 4;
            float4 v = (l < L_) ? *(const float4*)(xb + (size_t)l * D_ + d0 + d_loc)
                                : make_float4(0.f, 0.f, 0.f, 0.f);
            short s0 = f2bf(v.x), s1 = f2bf(v.y), s2 = f2bf(v.z), s3 = f2bf(v.w);
            t[l_loc][d_loc + 0] = *reinterpret_cast<__hip_bfloat16*>(&s0);
            t[l_loc][d_loc + 1] = *reinterpret_cast<__hip_bfloat16*>(&s1);
            t[l_loc][d_loc + 2] = *reinterpret_cast<__hip_bfloat16*>(&s2);
            t[l_loc][d_loc + 3] = *reinterpret_cast<__hip_bfloat16*>(&s3);
            if (l < L_) {
                union { short s[4]; unsigned long long u; } pk;
                pk.s[0] = s0; pk.s[1] = s1; pk.s[2] = s2; pk.s[3] = s3;
                *(unsigned long long*)(cat + ((size_t)bl * L_ + l) * CATW + 512 + d0 + d_loc) = pk.u;
            }
        }
        __syncthreads();
        int dl = tid >> 2, seg = tid & 3;
        short8 lo, hi;
        #pragma unroll
        for (int j = 0; j < 8; ++j) {
            __hip_bfloat16 a = t[seg * 16 + j][dl];
            __hip_bfloat16 bswap = t[seg * 16 + 8 + j][dl];
            lo[j] = *reinterpret_cast<short*>(&a);
            hi[j] = *reinterpret_cast<short*>(&bswap);
        }
        __hip_bfloat16* dst = xTb + ((size_t)bl * D_ + d0 + dl) * LP + l0 + seg * 16;
        *(short8*)dst = lo;
        *(short8*)(dst + 8) = hi;
        __syncthreads();
    }
}

// ---------------- fused attention: block per batch, 4 waves, MFMA ----------------
__global__ __launch_bounds__(256) void attn_kernel(
    const float* __restrict__ x, const float* __restrict__ pe,
    const int* __restrict__ text_len, const __hip_bfloat16* __restrict__ xTb,
    __hip_bfloat16* __restrict__ cat, int bh)
{
    __shared__ __align__(16) char sm[16384 + 32768];
    char* XP = sm;             // [128][64] bf16, swizzled, rowbytes=128
    char* P  = sm + 16384;     // [128][128] bf16, swizzled, rowbytes=256
    const int bl = blockIdx.x;
    const int b = bh * HB + bl;
    const int len = text_len[b];
    const int tid = threadIdx.x;
    const int w = tid >> 6, g = (tid >> 4) & 3, cl = tid & 15;
    const float* xb = x + (size_t)b * L_ * D_;

    f32x4 accS[2][8];
    const f32x4 fz = {0.f, 0.f, 0.f, 0.f};
    #pragma unroll
    for (int i = 0; i < 2; ++i)
        #pragma unroll
        for (int j = 0; j < 8; ++j) accS[i][j] = fz;

    // ---- phase A: S = xp @ xp^T ----
    for (int kc = 0; kc < D_; kc += 64) {
        #pragma unroll
        for (int i = 0; i < 4; ++i) {
            int c = tid + 256 * i;
            int row = c >> 3, k8d = c & 7;
            int k = kc + 8 * (k8d ^ (row & 7));
            short8 h;
            if (row < L_) {
                const float* px = xb + (size_t)row * D_ + k;
                const float* pp = pe + row * D_ + k;
                float4 a0 = *(const float4*)px, a1 = *(const float4*)(px + 4);
                float4 b0 = *(const float4*)pp, b1 = *(const float4*)(pp + 4);
                h[0] = f2bf(a0.x + b0.x); h[1] = f2bf(a0.y + b0.y);
                h[2] = f2bf(a0.z + b0.z); h[3] = f2bf(a0.w + b0.w);
                h[4] = f2bf(a1.x + b1.x); h[5] = f2bf(a1.y + b1.y);
                h[6] = f2bf(a1.z + b1.z); h[7] = f2bf(a1.w + b1.w);
            } else {
                #pragma unroll
                for (int q = 0; q < 8; ++q) h[q] = 0;
            }
            *(short8*)(XP + row * 128 + 16 * k8d) = h;
        }
        __syncthreads();
        #pragma unroll
        for (int kt = 0; kt < 2; ++kt) {
            short8 a[2];
            #pragma unroll
            for (int rt = 0; rt < 2; ++rt) {
                int r = 32 * w + 16 * rt + cl;
                a[rt] = *(const short8*)(XP + r * 128 + ((16 * g + 64 * kt) ^ ((r & 7) << 4)));
            }
            #pragma unroll
            for (int ct = 0; ct < 8; ++ct) {
                int m = 16 * ct + cl;
                short8 bb = *(const short8*)(XP + m * 128 + ((16 * g + 64 * kt) ^ ((m & 7) << 4)));
                accS[0][ct] = mfma16(a[0], bb, accS[0][ct]);
                accS[1][ct] = mfma16(a[1], bb, accS[1][ct]);
            }
        }
        __syncthreads();
    }

    // ---- phase B: masked softmax (reference MASK_FILL=1e-10, pads excluded) ----
    #pragma unroll
    for (int rt = 0; rt < 2; ++rt) {
        #pragma unroll
        for (int reg = 0; reg < 4; ++reg) {
            int rl = 32 * w + 16 * rt + 4 * g + reg;
            float s[8];
            #pragma unroll
            for (int ct = 0; ct < 8; ++ct) {
                int col = 16 * ct + cl;
                float v = accS[rt][ct][reg];
                if (col >= L_) v = -INFINITY;                  // padding: excluded
                else if (rl >= len || col >= len) v = 1e-10f;  // MASK_FILL
                s[ct] = v;
            }
            float mx = s[0];
            #pragma unroll
            for (int ct = 1; ct < 8; ++ct) mx = fmaxf(mx, s[ct]);
            mx = fmaxf(mx, __shfl_xor(mx, 1));
            mx = fmaxf(mx, __shfl_xor(mx, 2));
            mx = fmaxf(mx, __shfl_xor(mx, 4));
            mx = fmaxf(mx, __shfl_xor(mx, 8));
            float e[8], sum = 0.f;
            #pragma unroll
            for (int ct = 0; ct < 8; ++ct) { e[ct] = __expf(s[ct] - mx); sum += e[ct]; }
            sum += __shfl_xor(sum, 1);
            sum += __shfl_xor(sum, 2);
            sum += __shfl_xor(sum, 4);
            sum += __shfl_xor(sum, 8);
            float inv = 1.f / sum;
            #pragma unroll
            for (int ct = 0; ct < 8; ++ct) {
                int col = 16 * ct + cl;
                *(short*)(P + rl * 256 + ((col * 2) ^ ((rl & 7) << 4))) = f2bf(e[ct] * inv);
            }
        }
    }
    // P rows [32w,32w+32) are written and read only by wave w: no barrier needed.

    // ---- phase C: message = P @ x -> cat[:,0:512] ----
    const __hip_bfloat16* xT = xTb + (size_t)bl * D_ * LP;
    for (int nc = 0; nc < 4; ++nc) {
        f32x4 accM[2][8];
        #pragma unroll
        for (int i = 0; i < 2; ++i)
            #pragma unroll
            for (int j = 0; j < 8; ++j) accM[i][j] = fz;
        #pragma unroll
        for (int kt = 0; kt < 4; ++kt) {
            short8 a[2];
            #pragma unroll
            for (int rt = 0; rt < 2; ++rt) {
                int r = 32 * w + 16 * rt + cl;
                a[rt] = *(const short8*)(P + r * 256 + ((16 * g + 64 * kt) ^ ((r & 7) << 4)));
            }
            #pragma unroll
            for (int nt = 0; nt < 8; ++nt) {
                int d = nc * 128 + nt * 16 + cl;
                short8 bb = *(const short8*)(xT + (size_t)d * LP + 8 * g + 32 * kt);
                accM[0][nt] = mfma16(a[0], bb, accM[0][nt]);
                accM[1][nt] = mfma16(a[1], bb, accM[1][nt]);
            }
        }
        #pragma unroll
        for (int rt = 0; rt < 2; ++rt) {
            #pragma unroll
            for (int nt = 0; nt < 8; ++nt) {
                #pragma unroll
                for (int reg = 0; reg < 4; ++reg) {
                    int rl = 32 * w + 16 * rt + 4 * g + reg;
                    if (rl < L_) {
                        int d = nc * 128 + nt * 16 + cl;
                        cat[((size_t)bl * L_ + rl) * CATW + d] = __float2bfloat16(accM[rt][nt][reg]);
                    }
                }
            }
        }
    }
}

// ------- 256x256 BK=64 8-wave GEMM, m201-style 8-phase counted-vmcnt schedule -------
// MODE 0: N=1024, B=Wur^T, A = cat[:,0:1024]; epilogue sigmoid -> upd / xr.
// MODE 1: N=512,  B=Wo^T,  A = cat cols {0:512, 1024:1536}; epilogue GRU combine.
// Staging: 1 half-tile (2 loads/wave) per phase, landing in a region freed one
// phase earlier: P1->A0(t+1), P2->A1(t+1) [slot s^1, freed at t-1 P3];
// P3->B0(t+2), P4->B1(t+2) [slot s, freed at P2]. vmcnt(4) once per K-tile.
template<int MODE>
__global__ __launch_bounds__(512, 1) void gemm_gates(
    const __hip_bfloat16* __restrict__ cat,
    const __hip_bfloat16* __restrict__ Wt,
    const float* __restrict__ bias0, const float* __restrict__ bias1,
    const float* __restrict__ xsrc,         // f32 x rows (half-local base)
    __hip_bfloat16* __restrict__ upd,       // MODE0: write; MODE1: read
    __hip_bfloat16* __restrict__ catw,      // MODE0: xr writes into cat[:,1024:]
    float* __restrict__ xdst)               // MODE1: x output (half-local base)
{
    __shared__ __align__(16) char sm[131072];
    const int tid = threadIdx.x;
    const int lane = tid & 63;
    const int wid = tid >> 6;
    const int wr = wid >> 2, wc = wid & 3;
    const int g = lane >> 4, cl = lane & 15;
    constexpr int NY = (MODE == 0) ? 4 : 2;
    const int cpx = gridDim.x >> 3;
    const int bid = blockIdx.x;
    const int swz = (bid & 7) * cpx + (bid >> 3);   // bijective: grid % 8 == 0
    const int bx = swz / NY, by = swz % NY;
    const size_t R0 = (size_t)bx * 256;
    const int col0 = by * 256;

    // per-thread staging geometry (2 loads per half-tile per thread)
    int srow[2], soff[2];
    #pragma unroll
    for (int i = 0; i < 2; ++i) {
        int c = tid + 512 * i;
        srow[i] = c >> 3;                            // 0..127 within half
        soff[i] = 8 * ((c & 7) ^ ((c >> 3) & 7));    // pre-swizzled k offset
    }

    auto stageA = [&](int tile, int h) {
        const int kc = tile * 64;
        const int kb = (MODE == 0) ? kc : (kc < 512 ? kc : kc + 512);
        char* dst = sm + ((tile & 1) << 16) + h * 16384;
        const __hip_bfloat16* srcb = cat + (R0 + h * 128) * CATW + kb;
        #pragma unroll
        for (int i = 0; i < 2; ++i) {
            int c = tid + 512 * i;
            cp16(dst + c * 16, srcb + (size_t)srow[i] * CATW + soff[i]);
        }
    };
    auto stageB = [&](int tile, int h) {
        const int kc = tile * 64;
        char* dst = sm + ((tile & 1) << 16) + 32768 + h * 16384;
        const __hip_bfloat16* srcb = Wt + (size_t)(col0 + h * 128) * 1024 + kc;
        #pragma unroll
        for (int i = 0; i < 2; ++i) {
            int c = tid + 512 * i;
            cp16(dst + c * 16, srcb + (size_t)srow[i] * 1024 + soff[i]);
        }
    };

    f32x4 acc[8][4];
    const f32x4 fz = {0.f, 0.f, 0.f, 0.f};
    #pragma unroll
    for (int i = 0; i < 8; ++i)
        #pragma unroll
        for (int j = 0; j < 4; ++j) acc[i][j] = fz;

    // prologue: tile0 fully, tile1 B-halves; A-halves of tile1 staged in group 0
    stageA(0, 0); stageA(0, 1); stageB(0, 0); stageB(0, 1);
    stageB(1, 0); stageB(1, 1);
    asm volatile("s_waitcnt vmcnt(4)" ::: "memory");   // tile0 landed (t1 B in flight)
    __builtin_amdgcn_sched_barrier(0);
    __builtin_amdgcn_s_barrier();

    short8 aA[4][2], bA[2][2], bB[2][2];

    #pragma unroll 1
    for (int t = 0; t < 16; ++t) {
        char* Ab = sm + ((t & 1) << 16);
        char* Bb = Ab + 32768;

        // ---- P1: read aA(rt0-3) + bA(ct0-1); stage A0(t+1); MFMA Q0 ----
        #pragma unroll
        for (int rt = 0; rt < 4; ++rt) {
            int r = wr * 128 + rt * 16 + cl;
            #pragma unroll
            for (int kt = 0; kt < 2; ++kt)
                aA[rt][kt] = *(const short8*)(Ab + r * 128 + (((kt * 4 + g) ^ (r & 7)) << 4));
        }
        #pragma unroll
        for (int ct = 0; ct < 2; ++ct) {
            int n = wc * 64 + ct * 16 + cl;
            #pragma unroll
            for (int kt = 0; kt < 2; ++kt)
                bA[ct][kt] = *(const short8*)(Bb + n * 128 + (((kt * 4 + g) ^ (n & 7)) << 4));
        }
        if (t < 15) stageA(t + 1, 0);
        __builtin_amdgcn_s_barrier();
        asm volatile("s_waitcnt lgkmcnt(0)" ::: "memory");
        __builtin_amdgcn_sched_barrier(0);
        __builtin_amdgcn_s_setprio(1);
        #pragma unroll
        for (int rt = 0; rt < 4; ++rt)
            #pragma unroll
            for (int ct = 0; ct < 2; ++ct)
                #pragma unroll
                for (int kt = 0; kt < 2; ++kt)
                    acc[rt][ct] = mfma16(aA[rt][kt], bA[ct][kt], acc[rt][ct]);
        __builtin_amdgcn_s_setprio(0);
        __builtin_amdgcn_s_barrier();

        // ---- P2: read bB(ct2-3); stage A1(t+1); MFMA Q1 ----
        #pragma unroll
        for (int ct = 0; ct < 2; ++ct) {
            int n = wc * 64 + (ct + 2) * 16 + cl;
            #pragma unroll
            for (int kt = 0; kt < 2; ++kt)
                bB[ct][kt] = *(const short8*)(Bb + n * 128 + (((kt * 4 + g) ^ (n & 7)) << 4));
        }
        if (t < 15) stageA(t + 1, 1);
        __builtin_amdgcn_s_barrier();
        asm volatile("s_waitcnt lgkmcnt(0)" ::: "memory");
        __builtin_amdgcn_sched_barrier(0);
        __builtin_amdgcn_s_setprio(1);
        #pragma unroll
        for (int rt = 0; rt < 4; ++rt)
            #pragma unroll
            for (int ct = 0; ct < 2; ++ct)
                #pragma unroll
                for (int kt = 0; kt < 2; ++kt)
                    acc[rt][ct + 2] = mfma16(aA[rt][kt], bB[ct][kt], acc[rt][ct + 2]);
        __builtin_amdgcn_s_setprio(0);
        __builtin_amdgcn_s_barrier();

        // ---- P3: read aA(rt4-7); stage B0(t+2); MFMA Q2 ----
        #pragma unroll
        for (int rt = 0; rt < 4; ++rt) {
            int r = wr * 128 + (rt + 4) * 16 + cl;
            #pragma unroll
            for (int kt = 0; kt < 2; ++kt)
                aA[rt][kt] = *(const short8*)(Ab + r * 128 + (((kt * 4 + g) ^ (r & 7)) << 4));
        }
        if (t < 14) stageB(t + 2, 0);
        __builtin_amdgcn_s_barrier();
        asm volatile("s_waitcnt lgkmcnt(0)" ::: "memory");
        __builtin_amdgcn_sched_barrier(0);
        __builtin_amdgcn_s_setprio(1);
        #pragma unroll
        for (int rt = 0; rt < 4; ++rt)
            #pragma unroll
            for (int ct = 0; ct < 2; ++ct)
                #pragma unroll
                for (int kt = 0; kt < 2; ++kt)
                    acc[rt + 4][ct] = mfma16(aA[rt][kt], bA[ct][kt], acc[rt + 4][ct]);
        __builtin_amdgcn_s_setprio(0);
        __builtin_amdgcn_s_barrier();

        // ---- P4: stage B1(t+2); MFMA Q3; counted vmcnt ----
        if (t < 14) stageB(t + 2, 1);
        __builtin_amdgcn_s_barrier();
        __builtin_amdgcn_s_setprio(1);
        #pragma unroll
        for (int rt = 0; rt < 4; ++rt)
            #pragma unroll
            for (int ct = 0; ct < 2; ++ct)
                #pragma unroll
                for (int kt = 0; kt < 2; ++kt)
                    acc[rt + 4][ct + 2] = mfma16(aA[rt][kt], bB[ct][kt], acc[rt + 4][ct + 2]);
        __builtin_amdgcn_s_setprio(0);
        if (t < 14)      { asm volatile("s_waitcnt vmcnt(4)" ::: "memory"); }
        else if (t == 14){ asm volatile("s_waitcnt vmcnt(0)" ::: "memory"); }
        __builtin_amdgcn_sched_barrier(0);
        __builtin_amdgcn_s_barrier();
    }

    // ---- epilogue ----
    if (MODE == 0) {
        const bool isU = (col0 < 512);
        #pragma unroll
        for (int ct = 0; ct < 4; ++ct) {
            int colg = col0 + wc * 64 + ct * 16 + cl;
            float bb = isU ? bias0[colg] : bias1[colg - 512];
            #pragma unroll
            for (int rt = 0; rt < 8; ++rt) {
                #pragma unroll
                for (int reg = 0; reg < 4; ++reg) {
                    size_t grow = R0 + wr * 128 + rt * 16 + g * 4 + reg;
                    float v = 1.f / (1.f + __expf(-(acc[rt][ct][reg] + bb)));
                    if (isU) {
                        upd[grow * D_ + colg] = __float2bfloat16(v);
                    } else {
                        int c2 = colg - 512;
                        float xv = xsrc[grow * D_ + c2];
                        catw[grow * CATW + 1024 + c2] = __float2bfloat16(xv * v);
                    }
                }
            }
        }
    } else {
        #pragma unroll
        for (int ct = 0; ct < 4; ++ct) {
            int colg = col0 + wc * 64 + ct * 16 + cl;
            float bb = bias0[colg];
            #pragma unroll
            for (int rt = 0; rt < 8; ++rt) {
                #pragma unroll
                for (int reg = 0; reg < 4; ++reg) {
                    size_t grow = R0 + wr * 128 + rt * 16 + g * 4 + reg;
                    float cand = tanhf(acc[rt][ct][reg] + bb);
                    float u = __bfloat162float(upd[grow * D_ + colg]);
                    float xv = xsrc[grow * D_ + colg];
                    xdst[grow * D_ + colg] = xv + u * (cand - xv);
                }
            }
        }
    }
}

// ---------------- masked mean pooling ----------------
__global__ __launch_bounds__(256) void pool_kernel(
    const float* __restrict__ x, const int* __restrict__ text_len,
    float* __restrict__ seq)
{
    int b = blockIdx.x;
    int len = text_len[b];
    float invlen = 1.f / (float)len;
    const float* xb = x + (size_t)b * L_ * D_;
    for (int d = threadIdx.x; d < D_; d += 256) {
        float acc = 0.f;
        for (int l = 0; l < len; ++l)
            acc += xb[(size_t)l * D_ + d];
        seq[(size_t)b * D_ + d] = acc * invlen;
    }
}

extern "C" void kernel_launch(void* const* d_in, const int* in_sizes, int n_in,
                              void* d_out, int out_size, void* d_ws, size_t ws_size,
                              hipStream_t stream) {
    const float* x_in = (const float*)d_in[0];
    const int* text_len = (const int*)d_in[1];
    const float* W_r = (const float*)d_in[2];
    const float* b_r = (const float*)d_in[3];
    const float* W_u = (const float*)d_in[4];
    const float* b_u = (const float*)d_in[5];
    const float* W_o = (const float*)d_in[6];
    const float* b_o = (const float*)d_in[7];

    float* xwork = (float*)d_out;
    float* seq_out = (float*)d_out + XELEMS;

    char* ws = (char*)d_ws;
    float* pe            = (float*)ws;                         // 204800 B
    __hip_bfloat16* WurT = (__hip_bfloat16*)(ws + 204800);     // [1024][1024] bf16 (u rows 0-511, r rows 512-1023)
    __hip_bfloat16* WoT  = (__hip_bfloat16*)(ws + 2301952);    // [512][1024] bf16
    __hip_bfloat16* cat  = (__hip_bfloat16*)(ws + 3350528);    // [51200][1536] bf16
    char* unionR         = ws + 160636928ull;                  // 67108864 B
    __hip_bfloat16* xTb  = (__hip_bfloat16*)unionR;            // [512][512][128] bf16
    __hip_bfloat16* upd  = (__hip_bfloat16*)unionR;            // [51200][512] bf16 (aliased; disjoint lifetime)

    pe_kernel<<<(L_ * D_ + 255) / 256, 256, 0, stream>>>(pe);
    cvtw_kernel<<<2048, 256, 0, stream>>>(W_u, WurT);
    cvtw_kernel<<<2048, 256, 0, stream>>>(W_r, WurT + 512 * 1024);
    cvtw_kernel<<<2048, 256, 0, stream>>>(W_o, WoT);

    for (int layer = 0; layer < 2; ++layer) {
        const float* xs = layer ? (const float*)xwork : x_in;
        for (int h = 0; h < 2; ++h) {
            const float* xsh = xs + (size_t)h * HR * D_;
            float* xdh = xwork + (size_t)h * HR * D_;
            prep_xt_kernel<<<dim3(8, HB), 256, 0, stream>>>(xs, xTb, cat, h);
            attn_kernel<<<HB, 256, 0, stream>>>(xs, pe, text_len, xTb, cat, h);
            gemm_gates<0><<<800, 512, 0, stream>>>(cat, WurT, b_u, b_r, xsh, upd, cat, nullptr);
            gemm_gates<1><<<400, 512, 0, stream>>>(cat, WoT, b_o, nullptr, xsh, upd, nullptr, xdh);
        }
    }
    pool_kernel<<<B_, 256, 0, stream>>>(xwork, text_len, seq_out);
}

// Round 6
// 2352.895 us; speedup vs baseline: 1.2733x; 1.2548x over previous
//
#include <hip/hip_runtime.h>
#include <hip/hip_bf16.h>

// B=1024, L=100, D=512, 2 layers. Outputs: x'[B,L,D] f32 then seq_emb[B,D] f32.
#define B_ 1024
#define L_ 100
#define D_ 512
#define LP 128                    // padded L for MFMA tiles
#define ROWS (B_*L_)              // 102400
#define XELEMS ((size_t)ROWS*D_)  // 52428800
#define HB 512                    // batches per half
#define HR (HB*L_)                // rows per half = 51200
#define CATW 1536                 // cat row stride: [msg(512) | xbf16(512) | xr(512)]

typedef __attribute__((ext_vector_type(8))) short short8;
typedef __attribute__((ext_vector_type(4))) float f32x4;

__device__ __forceinline__ short f2bf(float f) {
    __hip_bfloat16 h = __float2bfloat16(f);
    return *reinterpret_cast<short*>(&h);
}

__device__ __forceinline__ void cp16(void* lds, const void* g) {
    __builtin_amdgcn_global_load_lds(
        (const __attribute__((address_space(1))) unsigned int*)g,
        (__attribute__((address_space(3))) unsigned int*)lds, 16, 0, 0);
}

__device__ __forceinline__ f32x4 mfma16(short8 a, short8 b, f32x4 c) {
    return __builtin_amdgcn_mfma_f32_16x16x32_bf16(a, b, c, 0, 0, 0);
}

// ---------------- positional encoding ----------------
__global__ __launch_bounds__(256) void pe_kernel(float* __restrict__ pe) {
    int idx = blockIdx.x * 256 + threadIdx.x;
    if (idx >= L_ * D_) return;
    int l = idx >> 9;
    int d = idx & 511;
    int i = d >> 1;
    float div = __expf((float)(2 * i) * (-9.210340371976184f / 512.0f));
    float angle = (float)l * div;
    pe[idx] = (d & 1) ? __cosf(angle) : __sinf(angle);
}

// ---------------- weight transpose+cvt: W[k][n] f32 -> Wt[n][k] bf16 ----------------
__global__ __launch_bounds__(256) void cvtw_kernel(const float* __restrict__ W,
                                                   __hip_bfloat16* __restrict__ Wt) {
    int idx = blockIdx.x * 256 + threadIdx.x;   // over 512*1024
    int n = idx >> 10, k = idx & 1023;
    Wt[idx] = __float2bfloat16(W[(size_t)k * D_ + n]);
}

// ---- per-batch transpose + cat x-copy: x[b][l][d] f32 -> xT[bl][d][lp128] bf16,
//      and cat[row][512+d] = bf16(x) ----
__global__ __launch_bounds__(256) void prep_xt_kernel(const float* __restrict__ x,
                                                      __hip_bfloat16* __restrict__ xTb,
                                                      __hip_bfloat16* __restrict__ cat,
                                                      int bh) {
    const int bl = blockIdx.y;            // local batch 0..511
    const int b = bh * HB + bl;
    const int d0 = blockIdx.x * 64;
    __shared__ __hip_bfloat16 t[64][66];
    const float* xb = x + (size_t)b * L_ * D_;
    const int tid = threadIdx.x;
    for (int l0 = 0; l0 < LP; l0 += 64) {
        int l_loc = tid >> 2;
        int dq = tid & 3;
        int l = l0 + l_loc;
        #pragma unroll
        for (int i = 0; i < 4; ++i) {
            int d_loc = (dq * 4 + i) * 4;
            float4 v = (l < L_) ? *(const float4*)(xb + (size_t)l * D_ + d0 + d_loc)
                                : make_float4(0.f, 0.f, 0.f, 0.f);
            short s0 = f2bf(v.x), s1 = f2bf(v.y), s2 = f2bf(v.z), s3 = f2bf(v.w);
            t[l_loc][d_loc + 0] = *reinterpret_cast<__hip_bfloat16*>(&s0);
            t[l_loc][d_loc + 1] = *reinterpret_cast<__hip_bfloat16*>(&s1);
            t[l_loc][d_loc + 2] = *reinterpret_cast<__hip_bfloat16*>(&s2);
            t[l_loc][d_loc + 3] = *reinterpret_cast<__hip_bfloat16*>(&s3);
            if (l < L_) {
                union { short s[4]; unsigned long long u; } pk;
                pk.s[0] = s0; pk.s[1] = s1; pk.s[2] = s2; pk.s[3] = s3;
                *(unsigned long long*)(cat + ((size_t)bl * L_ + l) * CATW + 512 + d0 + d_loc) = pk.u;
            }
        }
        __syncthreads();
        int dl = tid >> 2, seg = tid & 3;
        short8 lo, hi;
        #pragma unroll
        for (int j = 0; j < 8; ++j) {
            __hip_bfloat16 a = t[seg * 16 + j][dl];
            __hip_bfloat16 bswap = t[seg * 16 + 8 + j][dl];
            lo[j] = *reinterpret_cast<short*>(&a);
            hi[j] = *reinterpret_cast<short*>(&bswap);
        }
        __hip_bfloat16* dst = xTb + ((size_t)bl * D_ + d0 + dl) * LP + l0 + seg * 16;
        *(short8*)dst = lo;
        *(short8*)(dst + 8) = hi;
        __syncthreads();
    }
}

// ---------------- fused attention: block per batch, 4 waves, MFMA ----------------
__global__ __launch_bounds__(256) void attn_kernel(
    const float* __restrict__ x, const float* __restrict__ pe,
    const int* __restrict__ text_len, const __hip_bfloat16* __restrict__ xTb,
    __hip_bfloat16* __restrict__ cat, int bh)
{
    __shared__ __align__(16) char sm[16384 + 32768];
    char* XP = sm;             // [128][64] bf16, swizzled, rowbytes=128
    char* P  = sm + 16384;     // [128][128] bf16, swizzled, rowbytes=256
    const int bl = blockIdx.x;
    const int b = bh * HB + bl;
    const int len = text_len[b];
    const int tid = threadIdx.x;
    const int w = tid >> 6, g = (tid >> 4) & 3, cl = tid & 15;
    const float* xb = x + (size_t)b * L_ * D_;

    f32x4 accS[2][8];
    const f32x4 fz = {0.f, 0.f, 0.f, 0.f};
    #pragma unroll
    for (int i = 0; i < 2; ++i)
        #pragma unroll
        for (int j = 0; j < 8; ++j) accS[i][j] = fz;

    // ---- phase A: S = xp @ xp^T ----
    for (int kc = 0; kc < D_; kc += 64) {
        #pragma unroll
        for (int i = 0; i < 4; ++i) {
            int c = tid + 256 * i;
            int row = c >> 3, k8d = c & 7;
            int k = kc + 8 * (k8d ^ (row & 7));
            short8 h;
            if (row < L_) {
                const float* px = xb + (size_t)row * D_ + k;
                const float* pp = pe + row * D_ + k;
                float4 a0 = *(const float4*)px, a1 = *(const float4*)(px + 4);
                float4 b0 = *(const float4*)pp, b1 = *(const float4*)(pp + 4);
                h[0] = f2bf(a0.x + b0.x); h[1] = f2bf(a0.y + b0.y);
                h[2] = f2bf(a0.z + b0.z); h[3] = f2bf(a0.w + b0.w);
                h[4] = f2bf(a1.x + b1.x); h[5] = f2bf(a1.y + b1.y);
                h[6] = f2bf(a1.z + b1.z); h[7] = f2bf(a1.w + b1.w);
            } else {
                #pragma unroll
                for (int q = 0; q < 8; ++q) h[q] = 0;
            }
            *(short8*)(XP + row * 128 + 16 * k8d) = h;
        }
        __syncthreads();
        #pragma unroll
        for (int kt = 0; kt < 2; ++kt) {
            short8 a[2];
            #pragma unroll
            for (int rt = 0; rt < 2; ++rt) {
                int r = 32 * w + 16 * rt + cl;
                a[rt] = *(const short8*)(XP + r * 128 + ((16 * g + 64 * kt) ^ ((r & 7) << 4)));
            }
            #pragma unroll
            for (int ct = 0; ct < 8; ++ct) {
                int m = 16 * ct + cl;
                short8 bb = *(const short8*)(XP + m * 128 + ((16 * g + 64 * kt) ^ ((m & 7) << 4)));
                accS[0][ct] = mfma16(a[0], bb, accS[0][ct]);
                accS[1][ct] = mfma16(a[1], bb, accS[1][ct]);
            }
        }
        __syncthreads();
    }

    // ---- phase B: masked softmax (reference MASK_FILL=1e-10, pads excluded) ----
    #pragma unroll
    for (int rt = 0; rt < 2; ++rt) {
        #pragma unroll
        for (int reg = 0; reg < 4; ++reg) {
            int rl = 32 * w + 16 * rt + 4 * g + reg;
            float s[8];
            #pragma unroll
            for (int ct = 0; ct < 8; ++ct) {
                int col = 16 * ct + cl;
                float v = accS[rt][ct][reg];
                if (col >= L_) v = -INFINITY;                  // padding: excluded
                else if (rl >= len || col >= len) v = 1e-10f;  // MASK_FILL
                s[ct] = v;
            }
            float mx = s[0];
            #pragma unroll
            for (int ct = 1; ct < 8; ++ct) mx = fmaxf(mx, s[ct]);
            mx = fmaxf(mx, __shfl_xor(mx, 1));
            mx = fmaxf(mx, __shfl_xor(mx, 2));
            mx = fmaxf(mx, __shfl_xor(mx, 4));
            mx = fmaxf(mx, __shfl_xor(mx, 8));
            float e[8], sum = 0.f;
            #pragma unroll
            for (int ct = 0; ct < 8; ++ct) { e[ct] = __expf(s[ct] - mx); sum += e[ct]; }
            sum += __shfl_xor(sum, 1);
            sum += __shfl_xor(sum, 2);
            sum += __shfl_xor(sum, 4);
            sum += __shfl_xor(sum, 8);
            float inv = 1.f / sum;
            #pragma unroll
            for (int ct = 0; ct < 8; ++ct) {
                int col = 16 * ct + cl;
                *(short*)(P + rl * 256 + ((col * 2) ^ ((rl & 7) << 4))) = f2bf(e[ct] * inv);
            }
        }
    }
    // P rows [32w,32w+32) are written and read only by wave w: no barrier needed.

    // ---- phase C: message = P @ x -> cat[:,0:512] ----
    const __hip_bfloat16* xT = xTb + (size_t)bl * D_ * LP;
    for (int nc = 0; nc < 4; ++nc) {
        f32x4 accM[2][8];
        #pragma unroll
        for (int i = 0; i < 2; ++i)
            #pragma unroll
            for (int j = 0; j < 8; ++j) accM[i][j] = fz;
        #pragma unroll
        for (int kt = 0; kt < 4; ++kt) {
            short8 a[2];
            #pragma unroll
            for (int rt = 0; rt < 2; ++rt) {
                int r = 32 * w + 16 * rt + cl;
                a[rt] = *(const short8*)(P + r * 256 + ((16 * g + 64 * kt) ^ ((r & 7) << 4)));
            }
            #pragma unroll
            for (int nt = 0; nt < 8; ++nt) {
                int d = nc * 128 + nt * 16 + cl;
                short8 bb = *(const short8*)(xT + (size_t)d * LP + 8 * g + 32 * kt);
                accM[0][nt] = mfma16(a[0], bb, accM[0][nt]);
                accM[1][nt] = mfma16(a[1], bb, accM[1][nt]);
            }
        }
        #pragma unroll
        for (int rt = 0; rt < 2; ++rt) {
            #pragma unroll
            for (int nt = 0; nt < 8; ++nt) {
                #pragma unroll
                for (int reg = 0; reg < 4; ++reg) {
                    int rl = 32 * w + 16 * rt + 4 * g + reg;
                    if (rl < L_) {
                        int d = nc * 128 + nt * 16 + cl;
                        cat[((size_t)bl * L_ + rl) * CATW + d] = __float2bfloat16(accM[rt][nt][reg]);
                    }
                }
            }
        }
    }
}

// ------- 128x128 BK=64 4-wave single-buffer GEMM (m97 structure), all-cp16 staging ---
// MODE 0: N=1024, B=Wur^T, A = cat[:,0:1024]; epilogue sigmoid -> upd / cat-xr.
// MODE 1: N=512,  B=Wo^T,  A = cat cols {0:512, 1024:1536}; epilogue GRU combine.
// Grids: MODE0 = (HR/128)*(1024/128) = 3200, MODE1 = (HR/128)*(512/128) = 1600.
template<int MODE>
__global__ __launch_bounds__(256) void gemm_gates(
    const __hip_bfloat16* __restrict__ cat,
    const __hip_bfloat16* __restrict__ Wt,
    const float* __restrict__ bias0, const float* __restrict__ bias1,
    const float* __restrict__ xsrc,         // f32 x rows (half-local base)
    __hip_bfloat16* __restrict__ upd,       // MODE0: write; MODE1: read
    __hip_bfloat16* __restrict__ catw,      // MODE0: xr writes into cat[:,1024:]
    float* __restrict__ xdst)               // MODE1: x output (half-local base)
{
    __shared__ __align__(16) char sm[32768];
    char* As = sm;            // [128][64] bf16, swizzled, rowbytes=128
    char* Bs = sm + 16384;    // [128][64] bf16 (n-major), swizzled
    const int tid = threadIdx.x;
    const int w = tid >> 6, g = (tid >> 4) & 3, cl = tid & 15;
    const int wr = w >> 1, wc = w & 1;
    constexpr int NY = (MODE == 0) ? 8 : 4;
    const int cpx = gridDim.x >> 3;
    const int bid = blockIdx.x;
    const int swz = (bid & 7) * cpx + (bid >> 3);   // bijective: grid % 8 == 0
    const int bx = swz / NY, by = swz % NY;         // row-major logical: A-locality per XCD
    const size_t R0 = (size_t)bx * 128;
    const int col0 = by * 128;

    // per-thread staging geometry (4 cp16 per tile per thread)
    int srow[4], soff[4];
    #pragma unroll
    for (int i = 0; i < 4; ++i) {
        int c = tid + 256 * i;
        srow[i] = c >> 3;                            // 0..127
        soff[i] = 8 * ((c & 7) ^ ((c >> 3) & 7));    // pre-swizzled k offset
    }

    f32x4 acc[4][4];
    const f32x4 fz = {0.f, 0.f, 0.f, 0.f};
    #pragma unroll
    for (int i = 0; i < 4; ++i)
        #pragma unroll
        for (int j = 0; j < 4; ++j) acc[i][j] = fz;

    for (int t = 0; t < 16; ++t) {
        const int kc = t * 64;
        const int kb = (MODE == 0) ? kc : (kc < 512 ? kc : kc + 512);
        #pragma unroll
        for (int i = 0; i < 4; ++i) {
            int c = tid + 256 * i;
            cp16(As + c * 16, cat + (R0 + srow[i]) * CATW + kb + soff[i]);
            cp16(Bs + c * 16, Wt + (size_t)(col0 + srow[i]) * 1024 + kc + soff[i]);
        }
        __syncthreads();   // drains vmcnt: tile ready
        #pragma unroll
        for (int kt = 0; kt < 2; ++kt) {
            short8 aA[4], bb[4];
            #pragma unroll
            for (int rt = 0; rt < 4; ++rt) {
                int r = wr * 64 + rt * 16 + cl;
                aA[rt] = *(const short8*)(As + r * 128 + (((kt * 4 + g) ^ (r & 7)) << 4));
            }
            #pragma unroll
            for (int ct = 0; ct < 4; ++ct) {
                int n = wc * 64 + ct * 16 + cl;
                bb[ct] = *(const short8*)(Bs + n * 128 + (((kt * 4 + g) ^ (n & 7)) << 4));
            }
            #pragma unroll
            for (int rt = 0; rt < 4; ++rt)
                #pragma unroll
                for (int ct = 0; ct < 4; ++ct)
                    acc[rt][ct] = mfma16(aA[rt], bb[ct], acc[rt][ct]);
        }
        __syncthreads();   // reads consumed; safe to overwrite next iter
    }

    // ---- epilogue ----
    if (MODE == 0) {
        #pragma unroll
        for (int ct = 0; ct < 4; ++ct) {
            int colg = col0 + wc * 64 + ct * 16 + cl;     // 0..1023
            const bool isU = (colg < 512);
            float bb = isU ? bias0[colg] : bias1[colg - 512];
            #pragma unroll
            for (int rt = 0; rt < 4; ++rt) {
                #pragma unroll
                for (int reg = 0; reg < 4; ++reg) {
                    size_t grow = R0 + wr * 64 + rt * 16 + g * 4 + reg;
                    float v = 1.f / (1.f + __expf(-(acc[rt][ct][reg] + bb)));
                    if (isU) {
                        upd[grow * D_ + colg] = __float2bfloat16(v);
                    } else {
                        int c2 = colg - 512;
                        float xv = __bfloat162float(cat[grow * CATW + 512 + c2]);
                        catw[grow * CATW + 1024 + c2] = __float2bfloat16(xv * v);
                    }
                }
            }
        }
    } else {
        #pragma unroll
        for (int ct = 0; ct < 4; ++ct) {
            int colg = col0 + wc * 64 + ct * 16 + cl;     // 0..511
            float bb = bias0[colg];
            #pragma unroll
            for (int rt = 0; rt < 4; ++rt) {
                #pragma unroll
                for (int reg = 0; reg < 4; ++reg) {
                    size_t grow = R0 + wr * 64 + rt * 16 + g * 4 + reg;
                    float z = acc[rt][ct][reg] + bb;
                    // tanh(z) = 1 - 2/(1+e^{2z}); exact at saturation
                    float cand = 1.f - 2.f * __fdividef(1.f, 1.f + __expf(2.f * z));
                    float u = __bfloat162float(upd[grow * D_ + colg]);
                    float xv = xsrc[grow * D_ + colg];
                    xdst[grow * D_ + colg] = xv + u * (cand - xv);
                }
            }
        }
    }
}

// ---------------- masked mean pooling ----------------
__global__ __launch_bounds__(256) void pool_kernel(
    const float* __restrict__ x, const int* __restrict__ text_len,
    float* __restrict__ seq)
{
    int b = blockIdx.x;
    int len = text_len[b];
    float invlen = 1.f / (float)len;
    const float* xb = x + (size_t)b * L_ * D_;
    for (int d = threadIdx.x; d < D_; d += 256) {
        float acc = 0.f;
        for (int l = 0; l < len; ++l)
            acc += xb[(size_t)l * D_ + d];
        seq[(size_t)b * D_ + d] = acc * invlen;
    }
}

extern "C" void kernel_launch(void* const* d_in, const int* in_sizes, int n_in,
                              void* d_out, int out_size, void* d_ws, size_t ws_size,
                              hipStream_t stream) {
    const float* x_in = (const float*)d_in[0];
    const int* text_len = (const int*)d_in[1];
    const float* W_r = (const float*)d_in[2];
    const float* b_r = (const float*)d_in[3];
    const float* W_u = (const float*)d_in[4];
    const float* b_u = (const float*)d_in[5];
    const float* W_o = (const float*)d_in[6];
    const float* b_o = (const float*)d_in[7];

    float* xwork = (float*)d_out;
    float* seq_out = (float*)d_out + XELEMS;

    char* ws = (char*)d_ws;
    float* pe            = (float*)ws;                         // 204800 B
    __hip_bfloat16* WurT = (__hip_bfloat16*)(ws + 204800);     // [1024][1024] bf16 (u rows 0-511, r rows 512-1023)
    __hip_bfloat16* WoT  = (__hip_bfloat16*)(ws + 2301952);    // [512][1024] bf16
    __hip_bfloat16* cat  = (__hip_bfloat16*)(ws + 3350528);    // [51200][1536] bf16
    char* unionR         = ws + 160636928ull;                  // 67108864 B
    __hip_bfloat16* xTb  = (__hip_bfloat16*)unionR;            // [512][512][128] bf16
    __hip_bfloat16* upd  = (__hip_bfloat16*)unionR;            // [51200][512] bf16 (aliased; disjoint lifetime)

    pe_kernel<<<(L_ * D_ + 255) / 256, 256, 0, stream>>>(pe);
    cvtw_kernel<<<2048, 256, 0, stream>>>(W_u, WurT);
    cvtw_kernel<<<2048, 256, 0, stream>>>(W_r, WurT + 512 * 1024);
    cvtw_kernel<<<2048, 256, 0, stream>>>(W_o, WoT);

    for (int layer = 0; layer < 2; ++layer) {
        const float* xs = layer ? (const float*)xwork : x_in;
        for (int h = 0; h < 2; ++h) {
            const float* xsh = xs + (size_t)h * HR * D_;
            float* xdh = xwork + (size_t)h * HR * D_;
            prep_xt_kernel<<<dim3(8, HB), 256, 0, stream>>>(xs, xTb, cat, h);
            attn_kernel<<<HB, 256, 0, stream>>>(xs, pe, text_len, xTb, cat, h);
            gemm_gates<0><<<3200, 256, 0, stream>>>(cat, WurT, b_u, b_r, xsh, upd, cat, nullptr);
            gemm_gates<1><<<1600, 256, 0, stream>>>(cat, WoT, b_o, nullptr, xsh, upd, nullptr, xdh);
        }
    }
    pool_kernel<<<B_, 256, 0, stream>>>(xwork, text_len, seq_out);
}

// Round 7
// 2086.324 us; speedup vs baseline: 1.4360x; 1.1278x over previous
//
#include <hip/hip_runtime.h>
#include <hip/hip_bf16.h>

// B=1024, L=100, D=512, 2 layers. Outputs: x'[B,L,D] f32 then seq_emb[B,D] f32.
#define B_ 1024
#define L_ 100
#define D_ 512
#define LP 128                    // padded L for MFMA tiles
#define ROWS (B_*L_)              // 102400
#define XELEMS ((size_t)ROWS*D_)  // 52428800
#define HB 512                    // batches per half
#define HR (HB*L_)                // rows per half = 51200
#define CATW 1536                 // cat row stride: [msg(512) | xbf16(512) | xr(512)]

typedef __attribute__((ext_vector_type(8))) short short8;
typedef __attribute__((ext_vector_type(4))) float f32x4;

__device__ __forceinline__ short f2bf(float f) {
    __hip_bfloat16 h = __float2bfloat16(f);
    return *reinterpret_cast<short*>(&h);
}
__device__ __forceinline__ float bf2f(short s) {
    __hip_bfloat16 h = *reinterpret_cast<__hip_bfloat16*>(&s);
    return __bfloat162float(h);
}

__device__ __forceinline__ void cp16(void* lds, const void* g) {
    __builtin_amdgcn_global_load_lds(
        (const __attribute__((address_space(1))) unsigned int*)g,
        (__attribute__((address_space(3))) unsigned int*)lds, 16, 0, 0);
}

__device__ __forceinline__ f32x4 mfma16(short8 a, short8 b, f32x4 c) {
    return __builtin_amdgcn_mfma_f32_16x16x32_bf16(a, b, c, 0, 0, 0);
}

// ---------------- positional encoding ----------------
__global__ __launch_bounds__(256) void pe_kernel(float* __restrict__ pe) {
    int idx = blockIdx.x * 256 + threadIdx.x;
    if (idx >= L_ * D_) return;
    int l = idx >> 9;
    int d = idx & 511;
    int i = d >> 1;
    float div = __expf((float)(2 * i) * (-9.210340371976184f / 512.0f));
    float angle = (float)l * div;
    pe[idx] = (d & 1) ? __cosf(angle) : __sinf(angle);
}

// ---------------- weight transpose+cvt: W[k][n] f32 -> Wt[n][k] bf16 ----------------
__global__ __launch_bounds__(256) void cvtw_kernel(const float* __restrict__ W,
                                                   __hip_bfloat16* __restrict__ Wt) {
    int idx = blockIdx.x * 256 + threadIdx.x;   // over 512*1024
    int n = idx >> 10, k = idx & 1023;
    Wt[idx] = __float2bfloat16(W[(size_t)k * D_ + n]);
}

// ---- per-batch transpose: x -> xT[bl][d][lp128] bf16 (+ cat-x write on f32 path) ----
// BF16IN=0: read x_in f32, write cat[:,512:1024]=bf16(x) too.
// BF16IN=1: read cat[:,512:1024] bf16 (current layer input); no cat write.
template<int BF16IN>
__global__ __launch_bounds__(256) void prep_xt_kernel(const float* __restrict__ x,
                                                      __hip_bfloat16* __restrict__ xTb,
                                                      __hip_bfloat16* __restrict__ cat,
                                                      int bh) {
    const int bl = blockIdx.y;            // local batch 0..511
    const int b = bh * HB + bl;
    const int d0 = blockIdx.x * 64;
    __shared__ __hip_bfloat16 t[64][66];
    const float* xb = x + (size_t)b * L_ * D_;
    const int tid = threadIdx.x;
    for (int l0 = 0; l0 < LP; l0 += 64) {
        int l_loc = tid >> 2;
        int dq = tid & 3;
        int l = l0 + l_loc;
        #pragma unroll
        for (int i = 0; i < 4; ++i) {
            int d_loc = (dq * 4 + i) * 4;
            if constexpr (BF16IN) {
                unsigned long long u = 0ull;
                if (l < L_)
                    u = *(const unsigned long long*)(cat + ((size_t)bl * L_ + l) * CATW + 512 + d0 + d_loc);
                union { unsigned long long u; short s[4]; } pk;
                pk.u = u;
                t[l_loc][d_loc + 0] = *reinterpret_cast<__hip_bfloat16*>(&pk.s[0]);
                t[l_loc][d_loc + 1] = *reinterpret_cast<__hip_bfloat16*>(&pk.s[1]);
                t[l_loc][d_loc + 2] = *reinterpret_cast<__hip_bfloat16*>(&pk.s[2]);
                t[l_loc][d_loc + 3] = *reinterpret_cast<__hip_bfloat16*>(&pk.s[3]);
            } else {
                float4 v = (l < L_) ? *(const float4*)(xb + (size_t)l * D_ + d0 + d_loc)
                                    : make_float4(0.f, 0.f, 0.f, 0.f);
                short s0 = f2bf(v.x), s1 = f2bf(v.y), s2 = f2bf(v.z), s3 = f2bf(v.w);
                t[l_loc][d_loc + 0] = *reinterpret_cast<__hip_bfloat16*>(&s0);
                t[l_loc][d_loc + 1] = *reinterpret_cast<__hip_bfloat16*>(&s1);
                t[l_loc][d_loc + 2] = *reinterpret_cast<__hip_bfloat16*>(&s2);
                t[l_loc][d_loc + 3] = *reinterpret_cast<__hip_bfloat16*>(&s3);
                if (l < L_) {
                    union { short s[4]; unsigned long long u; } pk;
                    pk.s[0] = s0; pk.s[1] = s1; pk.s[2] = s2; pk.s[3] = s3;
                    *(unsigned long long*)(cat + ((size_t)bl * L_ + l) * CATW + 512 + d0 + d_loc) = pk.u;
                }
            }
        }
        __syncthreads();
        int dl = tid >> 2, seg = tid & 3;
        short8 lo, hi;
        #pragma unroll
        for (int j = 0; j < 8; ++j) {
            __hip_bfloat16 a = t[seg * 16 + j][dl];
            __hip_bfloat16 bswap = t[seg * 16 + 8 + j][dl];
            lo[j] = *reinterpret_cast<short*>(&a);
            hi[j] = *reinterpret_cast<short*>(&bswap);
        }
        __hip_bfloat16* dst = xTb + ((size_t)bl * D_ + d0 + dl) * LP + l0 + seg * 16;
        *(short8*)dst = lo;
        *(short8*)(dst + 8) = hi;
        __syncthreads();
    }
}

// ---------------- fused attention: block per batch, 4 waves, MFMA ----------------
// BF16IN=0: x from f32 array; BF16IN=1: x from cat[:,512:1024] bf16.
template<int BF16IN>
__global__ __launch_bounds__(256) void attn_kernel(
    const float* __restrict__ x, const float* __restrict__ pe,
    const int* __restrict__ text_len, const __hip_bfloat16* __restrict__ xTb,
    __hip_bfloat16* __restrict__ cat, int bh)
{
    __shared__ __align__(16) char sm[16384 + 32768];
    char* XP = sm;             // [128][64] bf16, swizzled, rowbytes=128
    char* P  = sm + 16384;     // [128][128] bf16, swizzled, rowbytes=256
    const int bl = blockIdx.x;
    const int b = bh * HB + bl;
    const int len = text_len[b];
    const int tid = threadIdx.x;
    const int w = tid >> 6, g = (tid >> 4) & 3, cl = tid & 15;
    const float* xb = x + (size_t)b * L_ * D_;

    f32x4 accS[2][8];
    const f32x4 fz = {0.f, 0.f, 0.f, 0.f};
    #pragma unroll
    for (int i = 0; i < 2; ++i)
        #pragma unroll
        for (int j = 0; j < 8; ++j) accS[i][j] = fz;

    // ---- phase A: S = xp @ xp^T ----
    for (int kc = 0; kc < D_; kc += 64) {
        #pragma unroll
        for (int i = 0; i < 4; ++i) {
            int c = tid + 256 * i;
            int row = c >> 3, k8d = c & 7;
            int k = kc + 8 * (k8d ^ (row & 7));
            if (row < L_) {
                const float* pp = pe + row * D_ + k;
                float4 b0 = *(const float4*)pp, b1 = *(const float4*)(pp + 4);
                short8 h;
                if constexpr (BF16IN) {
                    short8 xv = *(const short8*)(cat + ((size_t)bl * L_ + row) * CATW + 512 + k);
                    h[0] = f2bf(bf2f(xv[0]) + b0.x); h[1] = f2bf(bf2f(xv[1]) + b0.y);
                    h[2] = f2bf(bf2f(xv[2]) + b0.z); h[3] = f2bf(bf2f(xv[3]) + b0.w);
                    h[4] = f2bf(bf2f(xv[4]) + b1.x); h[5] = f2bf(bf2f(xv[5]) + b1.y);
                    h[6] = f2bf(bf2f(xv[6]) + b1.z); h[7] = f2bf(bf2f(xv[7]) + b1.w);
                } else {
                    const float* px = xb + (size_t)row * D_ + k;
                    float4 a0 = *(const float4*)px, a1 = *(const float4*)(px + 4);
                    h[0] = f2bf(a0.x + b0.x); h[1] = f2bf(a0.y + b0.y);
                    h[2] = f2bf(a0.z + b0.z); h[3] = f2bf(a0.w + b0.w);
                    h[4] = f2bf(a1.x + b1.x); h[5] = f2bf(a1.y + b1.y);
                    h[6] = f2bf(a1.z + b1.z); h[7] = f2bf(a1.w + b1.w);
                }
                *(short8*)(XP + row * 128 + 16 * k8d) = h;
            } else if (kc == 0) {
                short8 h;
                #pragma unroll
                for (int q = 0; q < 8; ++q) h[q] = 0;
                *(short8*)(XP + row * 128 + 16 * k8d) = h;   // stays 0 for all kc
            }
        }
        __syncthreads();
        #pragma unroll
        for (int kt = 0; kt < 2; ++kt) {
            short8 a[2];
            #pragma unroll
            for (int rt = 0; rt < 2; ++rt) {
                int r = 32 * w + 16 * rt + cl;
                a[rt] = *(const short8*)(XP + r * 128 + ((16 * g + 64 * kt) ^ ((r & 7) << 4)));
            }
            #pragma unroll
            for (int ct = 0; ct < 8; ++ct) {
                int m = 16 * ct + cl;
                short8 bb = *(const short8*)(XP + m * 128 + ((16 * g + 64 * kt) ^ ((m & 7) << 4)));
                accS[0][ct] = mfma16(a[0], bb, accS[0][ct]);
                accS[1][ct] = mfma16(a[1], bb, accS[1][ct]);
            }
        }
        __syncthreads();
    }

    // ---- phase B: masked softmax (reference MASK_FILL=1e-10, pads excluded) ----
    #pragma unroll
    for (int rt = 0; rt < 2; ++rt) {
        #pragma unroll
        for (int reg = 0; reg < 4; ++reg) {
            int rl = 32 * w + 16 * rt + 4 * g + reg;
            float s[8];
            #pragma unroll
            for (int ct = 0; ct < 8; ++ct) {
                int col = 16 * ct + cl;
                float v = accS[rt][ct][reg];
                if (col >= L_) v = -INFINITY;                  // padding: excluded
                else if (rl >= len || col >= len) v = 1e-10f;  // MASK_FILL
                s[ct] = v;
            }
            float mx = s[0];
            #pragma unroll
            for (int ct = 1; ct < 8; ++ct) mx = fmaxf(mx, s[ct]);
            mx = fmaxf(mx, __shfl_xor(mx, 1));
            mx = fmaxf(mx, __shfl_xor(mx, 2));
            mx = fmaxf(mx, __shfl_xor(mx, 4));
            mx = fmaxf(mx, __shfl_xor(mx, 8));
            float e[8], sum = 0.f;
            #pragma unroll
            for (int ct = 0; ct < 8; ++ct) { e[ct] = __expf(s[ct] - mx); sum += e[ct]; }
            sum += __shfl_xor(sum, 1);
            sum += __shfl_xor(sum, 2);
            sum += __shfl_xor(sum, 4);
            sum += __shfl_xor(sum, 8);
            float inv = 1.f / sum;
            #pragma unroll
            for (int ct = 0; ct < 8; ++ct) {
                int col = 16 * ct + cl;
                *(short*)(P + rl * 256 + ((col * 2) ^ ((rl & 7) << 4))) = f2bf(e[ct] * inv);
            }
        }
    }
    // P rows [32w,32w+32) are written and read only by wave w: no barrier needed.

    // ---- phase C: message = P @ x -> cat[:,0:512] ----
    const __hip_bfloat16* xT = xTb + (size_t)bl * D_ * LP;
    for (int nc = 0; nc < 4; ++nc) {
        f32x4 accM[2][8];
        #pragma unroll
        for (int i = 0; i < 2; ++i)
            #pragma unroll
            for (int j = 0; j < 8; ++j) accM[i][j] = fz;
        #pragma unroll
        for (int kt = 0; kt < 4; ++kt) {
            short8 a[2];
            #pragma unroll
            for (int rt = 0; rt < 2; ++rt) {
                int r = 32 * w + 16 * rt + cl;
                a[rt] = *(const short8*)(P + r * 256 + ((16 * g + 64 * kt) ^ ((r & 7) << 4)));
            }
            #pragma unroll
            for (int nt = 0; nt < 8; ++nt) {
                int d = nc * 128 + nt * 16 + cl;
                short8 bb = *(const short8*)(xT + (size_t)d * LP + 8 * g + 32 * kt);
                accM[0][nt] = mfma16(a[0], bb, accM[0][nt]);
                accM[1][nt] = mfma16(a[1], bb, accM[1][nt]);
            }
        }
        #pragma unroll
        for (int rt = 0; rt < 2; ++rt) {
            #pragma unroll
            for (int nt = 0; nt < 8; ++nt) {
                #pragma unroll
                for (int reg = 0; reg < 4; ++reg) {
                    int rl = 32 * w + 16 * rt + 4 * g + reg;
                    if (rl < L_) {
                        int d = nc * 128 + nt * 16 + cl;
                        cat[((size_t)bl * L_ + rl) * CATW + d] = __float2bfloat16(accM[rt][nt][reg]);
                    }
                }
            }
        }
    }
}

// ------- 128x128 BK=64 4-wave single-buffer GEMM (m97 structure), all-cp16 staging ---
// MODE 0: N=1024, B=Wur^T, A = cat[:,0:1024]; epilogue sigmoid -> upd / cat-xr.
// MODE 1: N=512,  B=Wo^T,  A = cat cols {0:512, 1024:1536}; epilogue GRU combine.
//   LAST=0: write xnew bf16 in-place to cat[:,512:1024] (race-free: each cell
//           read+written only by its owning thread; A never reads cols 512:1024).
//   LAST=1: write xnew f32 to xdst (final output).
// Grids: MODE0 = 3200, MODE1 = 1600.
template<int MODE, int LAST>
__global__ __launch_bounds__(256) void gemm_gates(
    const __hip_bfloat16* __restrict__ cat,
    const __hip_bfloat16* __restrict__ Wt,
    const float* __restrict__ bias0, const float* __restrict__ bias1,
    __hip_bfloat16* __restrict__ upd,       // MODE0: write; MODE1: read
    __hip_bfloat16* __restrict__ catw,      // writable cat alias
    float* __restrict__ xdst)               // MODE1+LAST: f32 x output (half-local)
{
    __shared__ __align__(16) char sm[32768];
    char* As = sm;            // [128][64] bf16, swizzled, rowbytes=128
    char* Bs = sm + 16384;    // [128][64] bf16 (n-major), swizzled
    const int tid = threadIdx.x;
    const int w = tid >> 6, g = (tid >> 4) & 3, cl = tid & 15;
    const int wr = w >> 1, wc = w & 1;
    constexpr int NY = (MODE == 0) ? 8 : 4;
    const int cpx = gridDim.x >> 3;
    const int bid = blockIdx.x;
    const int swz = (bid & 7) * cpx + (bid >> 3);   // bijective: grid % 8 == 0
    const int bx = swz / NY, by = swz % NY;         // row-major logical: A-locality per XCD
    const size_t R0 = (size_t)bx * 128;
    const int col0 = by * 128;

    // per-thread staging geometry (4 cp16 per tile per thread)
    int srow[4], soff[4];
    #pragma unroll
    for (int i = 0; i < 4; ++i) {
        int c = tid + 256 * i;
        srow[i] = c >> 3;                            // 0..127
        soff[i] = 8 * ((c & 7) ^ ((c >> 3) & 7));    // pre-swizzled k offset
    }

    f32x4 acc[4][4];
    const f32x4 fz = {0.f, 0.f, 0.f, 0.f};
    #pragma unroll
    for (int i = 0; i < 4; ++i)
        #pragma unroll
        for (int j = 0; j < 4; ++j) acc[i][j] = fz;

    for (int t = 0; t < 16; ++t) {
        const int kc = t * 64;
        const int kb = (MODE == 0) ? kc : (kc < 512 ? kc : kc + 512);
        #pragma unroll
        for (int i = 0; i < 4; ++i) {
            int c = tid + 256 * i;
            cp16(As + c * 16, cat + (R0 + srow[i]) * CATW + kb + soff[i]);
            cp16(Bs + c * 16, Wt + (size_t)(col0 + srow[i]) * 1024 + kc + soff[i]);
        }
        __syncthreads();   // drains vmcnt: tile ready
        #pragma unroll
        for (int kt = 0; kt < 2; ++kt) {
            short8 aA[4], bb[4];
            #pragma unroll
            for (int rt = 0; rt < 4; ++rt) {
                int r = wr * 64 + rt * 16 + cl;
                aA[rt] = *(const short8*)(As + r * 128 + (((kt * 4 + g) ^ (r & 7)) << 4));
            }
            #pragma unroll
            for (int ct = 0; ct < 4; ++ct) {
                int n = wc * 64 + ct * 16 + cl;
                bb[ct] = *(const short8*)(Bs + n * 128 + (((kt * 4 + g) ^ (n & 7)) << 4));
            }
            #pragma unroll
            for (int rt = 0; rt < 4; ++rt)
                #pragma unroll
                for (int ct = 0; ct < 4; ++ct)
                    acc[rt][ct] = mfma16(aA[rt], bb[ct], acc[rt][ct]);
        }
        __syncthreads();   // reads consumed; safe to overwrite next iter
    }

    // ---- epilogue ----
    if (MODE == 0) {
        #pragma unroll
        for (int ct = 0; ct < 4; ++ct) {
            int colg = col0 + wc * 64 + ct * 16 + cl;     // 0..1023
            const bool isU = (colg < 512);
            float bb = isU ? bias0[colg] : bias1[colg - 512];
            #pragma unroll
            for (int rt = 0; rt < 4; ++rt) {
                #pragma unroll
                for (int reg = 0; reg < 4; ++reg) {
                    size_t grow = R0 + wr * 64 + rt * 16 + g * 4 + reg;
                    float v = 1.f / (1.f + __expf(-(acc[rt][ct][reg] + bb)));
                    if (isU) {
                        upd[grow * D_ + colg] = __float2bfloat16(v);
                    } else {
                        int c2 = colg - 512;
                        float xv = __bfloat162float(cat[grow * CATW + 512 + c2]);
                        catw[grow * CATW + 1024 + c2] = __float2bfloat16(xv * v);
                    }
                }
            }
        }
    } else {
        #pragma unroll
        for (int ct = 0; ct < 4; ++ct) {
            int colg = col0 + wc * 64 + ct * 16 + cl;     // 0..511
            float bb = bias0[colg];
            #pragma unroll
            for (int rt = 0; rt < 4; ++rt) {
                #pragma unroll
                for (int reg = 0; reg < 4; ++reg) {
                    size_t grow = R0 + wr * 64 + rt * 16 + g * 4 + reg;
                    float z = acc[rt][ct][reg] + bb;
                    // tanh(z) = 1 - 2/(1+e^{2z}); exact at saturation
                    float cand = 1.f - 2.f * __fdividef(1.f, 1.f + __expf(2.f * z));
                    float u = __bfloat162float(upd[grow * D_ + colg]);
                    float xv = __bfloat162float(cat[grow * CATW + 512 + colg]);
                    float outv = xv + u * (cand - xv);
                    if (LAST) {
                        xdst[grow * D_ + colg] = outv;
                    } else {
                        catw[grow * CATW + 512 + colg] = __float2bfloat16(outv);
                    }
                }
            }
        }
    }
}

// ---------------- masked mean pooling ----------------
__global__ __launch_bounds__(256) void pool_kernel(
    const float* __restrict__ x, const int* __restrict__ text_len,
    float* __restrict__ seq)
{
    int b = blockIdx.x;
    int len = text_len[b];
    float invlen = 1.f / (float)len;
    const float* xb = x + (size_t)b * L_ * D_;
    for (int d = threadIdx.x; d < D_; d += 256) {
        float acc = 0.f;
        for (int l = 0; l < len; ++l)
            acc += xb[(size_t)l * D_ + d];
        seq[(size_t)b * D_ + d] = acc * invlen;
    }
}

extern "C" void kernel_launch(void* const* d_in, const int* in_sizes, int n_in,
                              void* d_out, int out_size, void* d_ws, size_t ws_size,
                              hipStream_t stream) {
    const float* x_in = (const float*)d_in[0];
    const int* text_len = (const int*)d_in[1];
    const float* W_r = (const float*)d_in[2];
    const float* b_r = (const float*)d_in[3];
    const float* W_u = (const float*)d_in[4];
    const float* b_u = (const float*)d_in[5];
    const float* W_o = (const float*)d_in[6];
    const float* b_o = (const float*)d_in[7];

    float* xwork = (float*)d_out;
    float* seq_out = (float*)d_out + XELEMS;

    char* ws = (char*)d_ws;
    float* pe            = (float*)ws;                         // 204800 B
    __hip_bfloat16* WurT = (__hip_bfloat16*)(ws + 204800);     // [1024][1024] bf16 (u rows 0-511, r rows 512-1023)
    __hip_bfloat16* WoT  = (__hip_bfloat16*)(ws + 2301952);    // [512][1024] bf16
    __hip_bfloat16* cat  = (__hip_bfloat16*)(ws + 3350528);    // [51200][1536] bf16 (per-half)
    char* unionR         = ws + 160636928ull;                  // 67108864 B
    __hip_bfloat16* xTb  = (__hip_bfloat16*)unionR;            // [512][512][128] bf16
    __hip_bfloat16* upd  = (__hip_bfloat16*)unionR;            // [51200][512] bf16 (aliased; disjoint lifetime)

    pe_kernel<<<(L_ * D_ + 255) / 256, 256, 0, stream>>>(pe);
    cvtw_kernel<<<2048, 256, 0, stream>>>(W_u, WurT);
    cvtw_kernel<<<2048, 256, 0, stream>>>(W_r, WurT + 512 * 1024);
    cvtw_kernel<<<2048, 256, 0, stream>>>(W_o, WoT);

    // half-outer order: cat persists per-half across both layers,
    // so the bf16 x-chain lives entirely in cat[:,512:1024].
    for (int h = 0; h < 2; ++h) {
        float* xdh = xwork + (size_t)h * HR * D_;
        // ---- layer 0: x from x_in f32 ----
        prep_xt_kernel<0><<<dim3(8, HB), 256, 0, stream>>>(x_in, xTb, cat, h);
        attn_kernel<0><<<HB, 256, 0, stream>>>(x_in, pe, text_len, xTb, cat, h);
        gemm_gates<0, 0><<<3200, 256, 0, stream>>>(cat, WurT, b_u, b_r, upd, cat, nullptr);
        gemm_gates<1, 0><<<1600, 256, 0, stream>>>(cat, WoT, b_o, nullptr, upd, cat, nullptr);
        // ---- layer 1: x from cat bf16 (written in-place by layer-0 MODE1) ----
        prep_xt_kernel<1><<<dim3(8, HB), 256, 0, stream>>>(nullptr, xTb, cat, h);
        attn_kernel<1><<<HB, 256, 0, stream>>>(nullptr, pe, text_len, xTb, cat, h);
        gemm_gates<0, 0><<<3200, 256, 0, stream>>>(cat, WurT, b_u, b_r, upd, cat, nullptr);
        gemm_gates<1, 1><<<1600, 256, 0, stream>>>(cat, WoT, b_o, nullptr, upd, cat, xdh);
    }
    pool_kernel<<<B_, 256, 0, stream>>>(xwork, text_len, seq_out);
}

// Round 8
// 1946.715 us; speedup vs baseline: 1.5390x; 1.0717x over previous
//
#include <hip/hip_runtime.h>
#include <hip/hip_bf16.h>

// B=1024, L=100, D=512, 2 layers. Outputs: x'[B,L,D] f32 then seq_emb[B,D] f32.
#define B_ 1024
#define L_ 100
#define D_ 512
#define LP 128                    // padded L for MFMA tiles
#define ROWS (B_*L_)              // 102400
#define XELEMS ((size_t)ROWS*D_)  // 52428800
#define HB 512                    // batches per half
#define HR (HB*L_)                // rows per half = 51200
#define CATW 1536                 // cat row stride: [msg(512) | xbf16(512) | xr(512)]

typedef __attribute__((ext_vector_type(8))) short short8;
typedef __attribute__((ext_vector_type(4))) float f32x4;

__device__ __forceinline__ short f2bf(float f) {
    __hip_bfloat16 h = __float2bfloat16(f);
    return *reinterpret_cast<short*>(&h);
}
__device__ __forceinline__ float bf2f(short s) {
    __hip_bfloat16 h = *reinterpret_cast<__hip_bfloat16*>(&s);
    return __bfloat162float(h);
}

__device__ __forceinline__ void cp16(void* lds, const void* g) {
    __builtin_amdgcn_global_load_lds(
        (const __attribute__((address_space(1))) unsigned int*)g,
        (__attribute__((address_space(3))) unsigned int*)lds, 16, 0, 0);
}

__device__ __forceinline__ f32x4 mfma16(short8 a, short8 b, f32x4 c) {
    return __builtin_amdgcn_mfma_f32_16x16x32_bf16(a, b, c, 0, 0, 0);
}

// ---------------- positional encoding ----------------
__global__ __launch_bounds__(256) void pe_kernel(float* __restrict__ pe) {
    int idx = blockIdx.x * 256 + threadIdx.x;
    if (idx >= L_ * D_) return;
    int l = idx >> 9;
    int d = idx & 511;
    int i = d >> 1;
    float div = __expf((float)(2 * i) * (-9.210340371976184f / 512.0f));
    float angle = (float)l * div;
    pe[idx] = (d & 1) ? __cosf(angle) : __sinf(angle);
}

// ---------------- weight transpose+cvt: W[k][n] f32 -> Wt[n][k] bf16 ----------------
__global__ __launch_bounds__(256) void cvtw_kernel(const float* __restrict__ W,
                                                   __hip_bfloat16* __restrict__ Wt) {
    int idx = blockIdx.x * 256 + threadIdx.x;   // over 512*1024
    int n = idx >> 10, k = idx & 1023;
    Wt[idx] = __float2bfloat16(W[(size_t)k * D_ + n]);
}

// ---- per-batch transpose: x -> xT[bl][d][lp128] bf16 (+ cat-x write on f32 path) ----
template<int BF16IN>
__global__ __launch_bounds__(256) void prep_xt_kernel(const float* __restrict__ x,
                                                      __hip_bfloat16* __restrict__ xTb,
                                                      __hip_bfloat16* __restrict__ cat,
                                                      int bh) {
    const int bl = blockIdx.y;            // local batch 0..511
    const int b = bh * HB + bl;
    const int d0 = blockIdx.x * 64;
    __shared__ __hip_bfloat16 t[64][66];
    const float* xb = x + (size_t)b * L_ * D_;
    const int tid = threadIdx.x;
    for (int l0 = 0; l0 < LP; l0 += 64) {
        int l_loc = tid >> 2;
        int dq = tid & 3;
        int l = l0 + l_loc;
        #pragma unroll
        for (int i = 0; i < 4; ++i) {
            int d_loc = (dq * 4 + i) * 4;
            if constexpr (BF16IN) {
                unsigned long long u = 0ull;
                if (l < L_)
                    u = *(const unsigned long long*)(cat + ((size_t)bl * L_ + l) * CATW + 512 + d0 + d_loc);
                union { unsigned long long u; short s[4]; } pk;
                pk.u = u;
                t[l_loc][d_loc + 0] = *reinterpret_cast<__hip_bfloat16*>(&pk.s[0]);
                t[l_loc][d_loc + 1] = *reinterpret_cast<__hip_bfloat16*>(&pk.s[1]);
                t[l_loc][d_loc + 2] = *reinterpret_cast<__hip_bfloat16*>(&pk.s[2]);
                t[l_loc][d_loc + 3] = *reinterpret_cast<__hip_bfloat16*>(&pk.s[3]);
            } else {
                float4 v = (l < L_) ? *(const float4*)(xb + (size_t)l * D_ + d0 + d_loc)
                                    : make_float4(0.f, 0.f, 0.f, 0.f);
                short s0 = f2bf(v.x), s1 = f2bf(v.y), s2 = f2bf(v.z), s3 = f2bf(v.w);
                t[l_loc][d_loc + 0] = *reinterpret_cast<__hip_bfloat16*>(&s0);
                t[l_loc][d_loc + 1] = *reinterpret_cast<__hip_bfloat16*>(&s1);
                t[l_loc][d_loc + 2] = *reinterpret_cast<__hip_bfloat16*>(&s2);
                t[l_loc][d_loc + 3] = *reinterpret_cast<__hip_bfloat16*>(&s3);
                if (l < L_) {
                    union { short s[4]; unsigned long long u; } pk;
                    pk.s[0] = s0; pk.s[1] = s1; pk.s[2] = s2; pk.s[3] = s3;
                    *(unsigned long long*)(cat + ((size_t)bl * L_ + l) * CATW + 512 + d0 + d_loc) = pk.u;
                }
            }
        }
        __syncthreads();
        int dl = tid >> 2, seg = tid & 3;
        short8 lo, hi;
        #pragma unroll
        for (int j = 0; j < 8; ++j) {
            __hip_bfloat16 a = t[seg * 16 + j][dl];
            __hip_bfloat16 bswap = t[seg * 16 + 8 + j][dl];
            lo[j] = *reinterpret_cast<short*>(&a);
            hi[j] = *reinterpret_cast<short*>(&bswap);
        }
        __hip_bfloat16* dst = xTb + ((size_t)bl * D_ + d0 + dl) * LP + l0 + seg * 16;
        *(short8*)dst = lo;
        *(short8*)(dst + 8) = hi;
        __syncthreads();
    }
}

// ---------------- fused attention: block per batch, 4 waves, MFMA ----------------
template<int BF16IN>
__global__ __launch_bounds__(256) void attn_kernel(
    const float* __restrict__ x, const float* __restrict__ pe,
    const int* __restrict__ text_len, const __hip_bfloat16* __restrict__ xTb,
    __hip_bfloat16* __restrict__ cat, int bh)
{
    __shared__ __align__(16) char sm[16384 + 32768];
    char* XP = sm;             // [128][64] bf16, swizzled, rowbytes=128 (phase A); T-buf (phase C)
    char* P  = sm + 16384;     // [128][128] bf16, swizzled, rowbytes=256
    const int bl = blockIdx.x;
    const int b = bh * HB + bl;
    const int len = text_len[b];
    const int tid = threadIdx.x;
    const int w = tid >> 6, g = (tid >> 4) & 3, cl = tid & 15;
    const int lane = tid & 63;
    const float* xb = x + (size_t)b * L_ * D_;

    f32x4 accS[2][8];
    const f32x4 fz = {0.f, 0.f, 0.f, 0.f};
    #pragma unroll
    for (int i = 0; i < 2; ++i)
        #pragma unroll
        for (int j = 0; j < 8; ++j) accS[i][j] = fz;

    // ---- phase A: S = xp @ xp^T ----
    for (int kc = 0; kc < D_; kc += 64) {
        #pragma unroll
        for (int i = 0; i < 4; ++i) {
            int c = tid + 256 * i;
            int row = c >> 3, k8d = c & 7;
            int k = kc + 8 * (k8d ^ (row & 7));
            if (row < L_) {
                const float* pp = pe + row * D_ + k;
                float4 b0 = *(const float4*)pp, b1 = *(const float4*)(pp + 4);
                short8 h;
                if constexpr (BF16IN) {
                    short8 xv = *(const short8*)(cat + ((size_t)bl * L_ + row) * CATW + 512 + k);
                    h[0] = f2bf(bf2f(xv[0]) + b0.x); h[1] = f2bf(bf2f(xv[1]) + b0.y);
                    h[2] = f2bf(bf2f(xv[2]) + b0.z); h[3] = f2bf(bf2f(xv[3]) + b0.w);
                    h[4] = f2bf(bf2f(xv[4]) + b1.x); h[5] = f2bf(bf2f(xv[5]) + b1.y);
                    h[6] = f2bf(bf2f(xv[6]) + b1.z); h[7] = f2bf(bf2f(xv[7]) + b1.w);
                } else {
                    const float* px = xb + (size_t)row * D_ + k;
                    float4 a0 = *(const float4*)px, a1 = *(const float4*)(px + 4);
                    h[0] = f2bf(a0.x + b0.x); h[1] = f2bf(a0.y + b0.y);
                    h[2] = f2bf(a0.z + b0.z); h[3] = f2bf(a0.w + b0.w);
                    h[4] = f2bf(a1.x + b1.x); h[5] = f2bf(a1.y + b1.y);
                    h[6] = f2bf(a1.z + b1.z); h[7] = f2bf(a1.w + b1.w);
                }
                *(short8*)(XP + row * 128 + 16 * k8d) = h;
            } else if (kc == 0) {
                short8 h;
                #pragma unroll
                for (int q = 0; q < 8; ++q) h[q] = 0;
                *(short8*)(XP + row * 128 + 16 * k8d) = h;   // stays 0 for all kc
            }
        }
        __syncthreads();
        #pragma unroll
        for (int kt = 0; kt < 2; ++kt) {
            short8 a[2];
            #pragma unroll
            for (int rt = 0; rt < 2; ++rt) {
                int r = 32 * w + 16 * rt + cl;
                a[rt] = *(const short8*)(XP + r * 128 + ((16 * g + 64 * kt) ^ ((r & 7) << 4)));
            }
            #pragma unroll
            for (int ct = 0; ct < 8; ++ct) {
                int m = 16 * ct + cl;
                short8 bb = *(const short8*)(XP + m * 128 + ((16 * g + 64 * kt) ^ ((m & 7) << 4)));
                accS[0][ct] = mfma16(a[0], bb, accS[0][ct]);
                accS[1][ct] = mfma16(a[1], bb, accS[1][ct]);
            }
        }
        __syncthreads();
    }

    // ---- phase B: masked softmax (reference MASK_FILL=1e-10, pads excluded) ----
    #pragma unroll
    for (int rt = 0; rt < 2; ++rt) {
        #pragma unroll
        for (int reg = 0; reg < 4; ++reg) {
            int rl = 32 * w + 16 * rt + 4 * g + reg;
            float s[8];
            #pragma unroll
            for (int ct = 0; ct < 8; ++ct) {
                int col = 16 * ct + cl;
                float v = accS[rt][ct][reg];
                if (col >= L_) v = -INFINITY;                  // padding: excluded
                else if (rl >= len || col >= len) v = 1e-10f;  // MASK_FILL
                s[ct] = v;
            }
            float mx = s[0];
            #pragma unroll
            for (int ct = 1; ct < 8; ++ct) mx = fmaxf(mx, s[ct]);
            mx = fmaxf(mx, __shfl_xor(mx, 1));
            mx = fmaxf(mx, __shfl_xor(mx, 2));
            mx = fmaxf(mx, __shfl_xor(mx, 4));
            mx = fmaxf(mx, __shfl_xor(mx, 8));
            float e[8], sum = 0.f;
            #pragma unroll
            for (int ct = 0; ct < 8; ++ct) { e[ct] = __expf(s[ct] - mx); sum += e[ct]; }
            sum += __shfl_xor(sum, 1);
            sum += __shfl_xor(sum, 2);
            sum += __shfl_xor(sum, 4);
            sum += __shfl_xor(sum, 8);
            float inv = 1.f / sum;
            #pragma unroll
            for (int ct = 0; ct < 8; ++ct) {
                int col = 16 * ct + cl;
                *(short*)(P + rl * 256 + ((col * 2) ^ ((rl & 7) << 4))) = f2bf(e[ct] * inv);
            }
        }
    }
    // P rows [32w,32w+32) are written and read only by wave w: no barrier needed.

    // ---- phase C: message = P @ x -> cat[:,0:512], per-wave LDS-transposed stores ----
    // (XP region is free after phase A's final barrier; 4KB per wave, wave-private.)
    const __hip_bfloat16* xT = xTb + (size_t)bl * D_ * LP;
    char* TW = XP + w * 4096;   // [16 rows][256B], XOR-swizzled
    for (int nc = 0; nc < 4; ++nc) {
        f32x4 accM[2][8];
        #pragma unroll
        for (int i = 0; i < 2; ++i)
            #pragma unroll
            for (int j = 0; j < 8; ++j) accM[i][j] = fz;
        #pragma unroll
        for (int kt = 0; kt < 4; ++kt) {
            short8 a[2];
            #pragma unroll
            for (int rt = 0; rt < 2; ++rt) {
                int r = 32 * w + 16 * rt + cl;
                a[rt] = *(const short8*)(P + r * 256 + ((16 * g + 64 * kt) ^ ((r & 7) << 4)));
            }
            #pragma unroll
            for (int nt = 0; nt < 8; ++nt) {
                int d = nc * 128 + nt * 16 + cl;
                short8 bb = *(const short8*)(xT + (size_t)d * LP + 8 * g + 32 * kt);
                accM[0][nt] = mfma16(a[0], bb, accM[0][nt]);
                accM[1][nt] = mfma16(a[1], bb, accM[1][nt]);
            }
        }
        #pragma unroll
        for (int rt = 0; rt < 2; ++rt) {
            // write 32 values into wave-private transpose buffer
            #pragma unroll
            for (int nt = 0; nt < 8; ++nt) {
                #pragma unroll
                for (int reg = 0; reg < 4; ++reg) {
                    int rloc = 4 * g + reg;              // 0..15
                    int cc = nt * 16 + cl;               // 0..127
                    *(short*)(TW + rloc * 256 + ((2 * cc) ^ ((rloc & 15) << 4))) =
                        f2bf(accM[rt][nt][reg]);
                }
            }
            asm volatile("s_waitcnt lgkmcnt(0)" ::: "memory");
            __builtin_amdgcn_sched_barrier(0);
            // read back coalesced: lane -> row r2 = lane>>2, col-quarter cq = lane&3
            int r2 = lane >> 2, cq = lane & 3;
            int rl = 32 * w + 16 * rt + r2;
            if (rl < L_) {
                #pragma unroll
                for (int j2 = 0; j2 < 4; ++j2) {
                    int byte = (cq * 64 + j2 * 16) ^ ((r2 & 15) << 4);
                    short8 v = *(const short8*)(TW + r2 * 256 + byte);
                    int d = nc * 128 + cq * 32 + j2 * 8;
                    *(short8*)(cat + ((size_t)bl * L_ + rl) * CATW + d) = v;
                }
            }
            asm volatile("s_waitcnt lgkmcnt(0)" ::: "memory");
            __builtin_amdgcn_sched_barrier(0);
        }
    }
}

// ------- 128x128 BK=64 4-wave single-buffer GEMM (m97 structure), all-cp16 staging ---
// Epilogue: activation -> LDS bf16 transpose (XOR-swizzled) -> coalesced vector IO.
// MODE 0: N=1024, B=Wur^T, A = cat[:,0:1024]; sigmoid -> upd / cat-xr.
// MODE 1: N=512,  B=Wo^T,  A = cat cols {0:512, 1024:1536}; GRU combine.
// Grids: MODE0 = 3200, MODE1 = 1600.
template<int MODE, int LAST>
__global__ __launch_bounds__(256) void gemm_gates(
    const __hip_bfloat16* __restrict__ cat,
    const __hip_bfloat16* __restrict__ Wt,
    const float* __restrict__ bias0, const float* __restrict__ bias1,
    __hip_bfloat16* __restrict__ upd,       // MODE0: write; MODE1: read
    __hip_bfloat16* __restrict__ catw,      // writable cat alias
    float* __restrict__ xdst)               // MODE1+LAST: f32 x output (half-local)
{
    __shared__ __align__(16) char sm[32768];
    char* As = sm;            // [128][64] bf16, swizzled, rowbytes=128
    char* Bs = sm + 16384;    // [128][64] bf16 (n-major), swizzled
    const int tid = threadIdx.x;
    const int w = tid >> 6, g = (tid >> 4) & 3, cl = tid & 15;
    const int wr = w >> 1, wc = w & 1;
    constexpr int NY = (MODE == 0) ? 8 : 4;
    const int cpx = gridDim.x >> 3;
    const int bid = blockIdx.x;
    const int swz = (bid & 7) * cpx + (bid >> 3);   // bijective: grid % 8 == 0
    const int bx = swz / NY, by = swz % NY;         // row-major logical: A-locality per XCD
    const size_t R0 = (size_t)bx * 128;
    const int col0 = by * 128;

    // per-thread staging geometry (4 cp16 per tile per thread)
    int srow[4], soff[4];
    #pragma unroll
    for (int i = 0; i < 4; ++i) {
        int c = tid + 256 * i;
        srow[i] = c >> 3;                            // 0..127
        soff[i] = 8 * ((c & 7) ^ ((c >> 3) & 7));    // pre-swizzled k offset
    }

    f32x4 acc[4][4];
    const f32x4 fz = {0.f, 0.f, 0.f, 0.f};
    #pragma unroll
    for (int i = 0; i < 4; ++i)
        #pragma unroll
        for (int j = 0; j < 4; ++j) acc[i][j] = fz;

    for (int t = 0; t < 16; ++t) {
        const int kc = t * 64;
        const int kb = (MODE == 0) ? kc : (kc < 512 ? kc : kc + 512);
        #pragma unroll
        for (int i = 0; i < 4; ++i) {
            int c = tid + 256 * i;
            cp16(As + c * 16, cat + (R0 + srow[i]) * CATW + kb + soff[i]);
            cp16(Bs + c * 16, Wt + (size_t)(col0 + srow[i]) * 1024 + kc + soff[i]);
        }
        __syncthreads();   // drains vmcnt: tile ready
        #pragma unroll
        for (int kt = 0; kt < 2; ++kt) {
            short8 aA[4], bb[4];
            #pragma unroll
            for (int rt = 0; rt < 4; ++rt) {
                int r = wr * 64 + rt * 16 + cl;
                aA[rt] = *(const short8*)(As + r * 128 + (((kt * 4 + g) ^ (r & 7)) << 4));
            }
            #pragma unroll
            for (int ct = 0; ct < 4; ++ct) {
                int n = wc * 64 + ct * 16 + cl;
                bb[ct] = *(const short8*)(Bs + n * 128 + (((kt * 4 + g) ^ (n & 7)) << 4));
            }
            #pragma unroll
            for (int rt = 0; rt < 4; ++rt)
                #pragma unroll
                for (int ct = 0; ct < 4; ++ct)
                    acc[rt][ct] = mfma16(aA[rt], bb[ct], acc[rt][ct]);
        }
        __syncthreads();   // reads consumed; safe to overwrite next iter
    }

    // ---- epilogue: activation -> LDS transpose -> coalesced stores ----
    char* T = sm;   // [128 rows][256B], reuses As/Bs (free after final barrier)
    #pragma unroll
    for (int ct = 0; ct < 4; ++ct) {
        int c = wc * 64 + ct * 16 + cl;        // local col 0..127
        int colg = col0 + c;
        float bb = (MODE == 0) ? ((col0 < 512) ? bias0[colg] : bias1[colg - 512])
                               : bias0[colg];
        #pragma unroll
        for (int rt = 0; rt < 4; ++rt) {
            #pragma unroll
            for (int reg = 0; reg < 4; ++reg) {
                int r = wr * 64 + rt * 16 + g * 4 + reg;
                float z = acc[rt][ct][reg] + bb;
                float v;
                if (MODE == 0) v = 1.f / (1.f + __expf(-z));                        // sigmoid
                else           v = 1.f - 2.f * __fdividef(1.f, 1.f + __expf(2.f * z)); // tanh
                *(short*)(T + r * 256 + ((2 * c) ^ ((r & 15) << 4))) = f2bf(v);
            }
        }
    }
    __syncthreads();
    {
        const int r = tid >> 1, hf = tid & 1;
        const size_t grow = R0 + r;
        #pragma unroll
        for (int j = 0; j < 8; ++j) {
            int byte = (hf * 128 + j * 16) ^ ((r & 15) << 4);
            short8 v = *(const short8*)(T + r * 256 + byte);
            int cloc = hf * 64 + j * 8;
            int colg = col0 + cloc;
            if (MODE == 0) {
                if (col0 < 512) {
                    *(short8*)(upd + grow * D_ + colg) = v;
                } else {
                    int c2 = colg - 512;
                    short8 xv = *(const short8*)(cat + grow * CATW + 512 + c2);
                    short8 o;
                    #pragma unroll
                    for (int q = 0; q < 8; ++q)
                        o[q] = f2bf(bf2f(xv[q]) * bf2f(v[q]));
                    *(short8*)(catw + grow * CATW + 1024 + c2) = o;
                }
            } else {
                short8 uv = *(const short8*)(upd + grow * D_ + colg);
                short8 xv = *(const short8*)(cat + grow * CATW + 512 + colg);
                if (LAST) {
                    float o[8];
                    #pragma unroll
                    for (int q = 0; q < 8; ++q) {
                        float u = bf2f(uv[q]), x_ = bf2f(xv[q]), cd = bf2f(v[q]);
                        o[q] = x_ + u * (cd - x_);
                    }
                    *(float4*)(xdst + grow * D_ + colg)     = make_float4(o[0], o[1], o[2], o[3]);
                    *(float4*)(xdst + grow * D_ + colg + 4) = make_float4(o[4], o[5], o[6], o[7]);
                } else {
                    short8 o;
                    #pragma unroll
                    for (int q = 0; q < 8; ++q) {
                        float u = bf2f(uv[q]), x_ = bf2f(xv[q]), cd = bf2f(v[q]);
                        o[q] = f2bf(x_ + u * (cd - x_));
                    }
                    *(short8*)(catw + grow * CATW + 512 + colg) = o;
                }
            }
        }
    }
}

// ---------------- masked mean pooling ----------------
__global__ __launch_bounds__(256) void pool_kernel(
    const float* __restrict__ x, const int* __restrict__ text_len,
    float* __restrict__ seq)
{
    int b = blockIdx.x;
    int len = text_len[b];
    float invlen = 1.f / (float)len;
    const float* xb = x + (size_t)b * L_ * D_;
    for (int d = threadIdx.x; d < D_; d += 256) {
        float acc = 0.f;
        for (int l = 0; l < len; ++l)
            acc += xb[(size_t)l * D_ + d];
        seq[(size_t)b * D_ + d] = acc * invlen;
    }
}

extern "C" void kernel_launch(void* const* d_in, const int* in_sizes, int n_in,
                              void* d_out, int out_size, void* d_ws, size_t ws_size,
                              hipStream_t stream) {
    const float* x_in = (const float*)d_in[0];
    const int* text_len = (const int*)d_in[1];
    const float* W_r = (const float*)d_in[2];
    const float* b_r = (const float*)d_in[3];
    const float* W_u = (const float*)d_in[4];
    const float* b_u = (const float*)d_in[5];
    const float* W_o = (const float*)d_in[6];
    const float* b_o = (const float*)d_in[7];

    float* xwork = (float*)d_out;
    float* seq_out = (float*)d_out + XELEMS;

    char* ws = (char*)d_ws;
    float* pe            = (float*)ws;                         // 204800 B
    __hip_bfloat16* WurT = (__hip_bfloat16*)(ws + 204800);     // [1024][1024] bf16 (u rows 0-511, r rows 512-1023)
    __hip_bfloat16* WoT  = (__hip_bfloat16*)(ws + 2301952);    // [512][1024] bf16
    __hip_bfloat16* cat  = (__hip_bfloat16*)(ws + 3350528);    // [51200][1536] bf16 (per-half)
    char* unionR         = ws + 160636928ull;                  // 67108864 B
    __hip_bfloat16* xTb  = (__hip_bfloat16*)unionR;            // [512][512][128] bf16
    __hip_bfloat16* upd  = (__hip_bfloat16*)unionR;            // [51200][512] bf16 (aliased; disjoint lifetime)

    pe_kernel<<<(L_ * D_ + 255) / 256, 256, 0, stream>>>(pe);
    cvtw_kernel<<<2048, 256, 0, stream>>>(W_u, WurT);
    cvtw_kernel<<<2048, 256, 0, stream>>>(W_r, WurT + 512 * 1024);
    cvtw_kernel<<<2048, 256, 0, stream>>>(W_o, WoT);

    // half-outer order: cat persists per-half across both layers,
    // so the bf16 x-chain lives entirely in cat[:,512:1024].
    for (int h = 0; h < 2; ++h) {
        float* xdh = xwork + (size_t)h * HR * D_;
        // ---- layer 0: x from x_in f32 ----
        prep_xt_kernel<0><<<dim3(8, HB), 256, 0, stream>>>(x_in, xTb, cat, h);
        attn_kernel<0><<<HB, 256, 0, stream>>>(x_in, pe, text_len, xTb, cat, h);
        gemm_gates<0, 0><<<3200, 256, 0, stream>>>(cat, WurT, b_u, b_r, upd, cat, nullptr);
        gemm_gates<1, 0><<<1600, 256, 0, stream>>>(cat, WoT, b_o, nullptr, upd, cat, nullptr);
        // ---- layer 1: x from cat bf16 (written in-place by layer-0 MODE1) ----
        prep_xt_kernel<1><<<dim3(8, HB), 256, 0, stream>>>(nullptr, xTb, cat, h);
        attn_kernel<1><<<HB, 256, 0, stream>>>(nullptr, pe, text_len, xTb, cat, h);
        gemm_gates<0, 0><<<3200, 256, 0, stream>>>(cat, WurT, b_u, b_r, upd, cat, nullptr);
        gemm_gates<1, 1><<<1600, 256, 0, stream>>>(cat, WoT, b_o, nullptr, upd, cat, xdh);
    }
    pool_kernel<<<B_, 256, 0, stream>>>(xwork, text_len, seq_out);
}

// Round 9
// 1777.681 us; speedup vs baseline: 1.6853x; 1.0951x over previous
//
#include <hip/hip_runtime.h>
#include <hip/hip_bf16.h>

// B=1024, L=100, D=512, 2 layers. Outputs: x'[B,L,D] f32 then seq_emb[B,D] f32.
#define B_ 1024
#define L_ 100
#define D_ 512
#define LP 128                    // padded L for MFMA tiles
#define ROWS (B_*L_)              // 102400
#define XELEMS ((size_t)ROWS*D_)  // 52428800
#define HB 512                    // batches per half
#define HR (HB*L_)                // rows per half = 51200
#define CATW 1536                 // cat row stride: [msg(512) | xbf16(512) | xr(512)]

typedef __attribute__((ext_vector_type(8))) short short8;
typedef __attribute__((ext_vector_type(4))) float f32x4;

__device__ __forceinline__ short f2bf(float f) {
    __hip_bfloat16 h = __float2bfloat16(f);
    return *reinterpret_cast<short*>(&h);
}
__device__ __forceinline__ float bf2f(short s) {
    __hip_bfloat16 h = *reinterpret_cast<__hip_bfloat16*>(&s);
    return __bfloat162float(h);
}

__device__ __forceinline__ void cp16(void* lds, const void* g) {
    __builtin_amdgcn_global_load_lds(
        (const __attribute__((address_space(1))) unsigned int*)g,
        (__attribute__((address_space(3))) unsigned int*)lds, 16, 0, 0);
}

__device__ __forceinline__ f32x4 mfma16(short8 a, short8 b, f32x4 c) {
    return __builtin_amdgcn_mfma_f32_16x16x32_bf16(a, b, c, 0, 0, 0);
}

// ---------------- positional encoding ----------------
__global__ __launch_bounds__(256) void pe_kernel(float* __restrict__ pe) {
    int idx = blockIdx.x * 256 + threadIdx.x;
    if (idx >= L_ * D_) return;
    int l = idx >> 9;
    int d = idx & 511;
    int i = d >> 1;
    float div = __expf((float)(2 * i) * (-9.210340371976184f / 512.0f));
    float angle = (float)l * div;
    pe[idx] = (d & 1) ? __cosf(angle) : __sinf(angle);
}

// ---------------- weight transpose+cvt: W[k][n] f32 -> Wt[n][k] bf16 ----------------
__global__ __launch_bounds__(256) void cvtw_kernel(const float* __restrict__ W,
                                                   __hip_bfloat16* __restrict__ Wt) {
    int idx = blockIdx.x * 256 + threadIdx.x;   // over 512*1024
    int n = idx >> 10, k = idx & 1023;
    Wt[idx] = __float2bfloat16(W[(size_t)k * D_ + n]);
}

// ---- per-batch transpose: x -> xT[bl][d][lp128] bf16 (+ cat-x write on f32 path) ----
template<int BF16IN>
__global__ __launch_bounds__(256) void prep_xt_kernel(const float* __restrict__ x,
                                                      __hip_bfloat16* __restrict__ xTb,
                                                      __hip_bfloat16* __restrict__ cat,
                                                      int bh) {
    const int bl = blockIdx.y;            // local batch 0..511
    const int b = bh * HB + bl;
    const int d0 = blockIdx.x * 64;
    __shared__ __hip_bfloat16 t[64][66];
    const float* xb = x + (size_t)b * L_ * D_;
    const int tid = threadIdx.x;
    for (int l0 = 0; l0 < LP; l0 += 64) {
        int l_loc = tid >> 2;
        int dq = tid & 3;
        int l = l0 + l_loc;
        #pragma unroll
        for (int i = 0; i < 4; ++i) {
            int d_loc = (dq * 4 + i) * 4;
            if constexpr (BF16IN) {
                unsigned long long u = 0ull;
                if (l < L_)
                    u = *(const unsigned long long*)(cat + ((size_t)bl * L_ + l) * CATW + 512 + d0 + d_loc);
                union { unsigned long long u; short s[4]; } pk;
                pk.u = u;
                t[l_loc][d_loc + 0] = *reinterpret_cast<__hip_bfloat16*>(&pk.s[0]);
                t[l_loc][d_loc + 1] = *reinterpret_cast<__hip_bfloat16*>(&pk.s[1]);
                t[l_loc][d_loc + 2] = *reinterpret_cast<__hip_bfloat16*>(&pk.s[2]);
                t[l_loc][d_loc + 3] = *reinterpret_cast<__hip_bfloat16*>(&pk.s[3]);
            } else {
                float4 v = (l < L_) ? *(const float4*)(xb + (size_t)l * D_ + d0 + d_loc)
                                    : make_float4(0.f, 0.f, 0.f, 0.f);
                short s0 = f2bf(v.x), s1 = f2bf(v.y), s2 = f2bf(v.z), s3 = f2bf(v.w);
                t[l_loc][d_loc + 0] = *reinterpret_cast<__hip_bfloat16*>(&s0);
                t[l_loc][d_loc + 1] = *reinterpret_cast<__hip_bfloat16*>(&s1);
                t[l_loc][d_loc + 2] = *reinterpret_cast<__hip_bfloat16*>(&s2);
                t[l_loc][d_loc + 3] = *reinterpret_cast<__hip_bfloat16*>(&s3);
                if (l < L_) {
                    union { short s[4]; unsigned long long u; } pk;
                    pk.s[0] = s0; pk.s[1] = s1; pk.s[2] = s2; pk.s[3] = s3;
                    *(unsigned long long*)(cat + ((size_t)bl * L_ + l) * CATW + 512 + d0 + d_loc) = pk.u;
                }
            }
        }
        __syncthreads();
        int dl = tid >> 2, seg = tid & 3;
        short8 lo, hi;
        #pragma unroll
        for (int j = 0; j < 8; ++j) {
            __hip_bfloat16 a = t[seg * 16 + j][dl];
            __hip_bfloat16 bswap = t[seg * 16 + 8 + j][dl];
            lo[j] = *reinterpret_cast<short*>(&a);
            hi[j] = *reinterpret_cast<short*>(&bswap);
        }
        __hip_bfloat16* dst = xTb + ((size_t)bl * D_ + d0 + dl) * LP + l0 + seg * 16;
        *(short8*)dst = lo;
        *(short8*)(dst + 8) = hi;
        __syncthreads();
    }
}

// ---------------- fused attention: block per batch, 4 waves, MFMA ----------------
template<int BF16IN>
__global__ __launch_bounds__(256) void attn_kernel(
    const float* __restrict__ x, const float* __restrict__ pe,
    const int* __restrict__ text_len, const __hip_bfloat16* __restrict__ xTb,
    __hip_bfloat16* __restrict__ cat, int bh)
{
    __shared__ __align__(16) char sm[16384 + 32768];
    char* XP = sm;             // [128][64] bf16, swizzled, rowbytes=128 (phase A); T-buf (phase C)
    char* P  = sm + 16384;     // [128][128] bf16, swizzled, rowbytes=256
    const int bl = blockIdx.x;
    const int b = bh * HB + bl;
    const int len = text_len[b];
    const int tid = threadIdx.x;
    const int w = tid >> 6, g = (tid >> 4) & 3, cl = tid & 15;
    const int lane = tid & 63;
    const float* xb = x + (size_t)b * L_ * D_;

    f32x4 accS[2][8];
    const f32x4 fz = {0.f, 0.f, 0.f, 0.f};
    #pragma unroll
    for (int i = 0; i < 2; ++i)
        #pragma unroll
        for (int j = 0; j < 8; ++j) accS[i][j] = fz;

    // ---- phase A: S = xp @ xp^T ----
    for (int kc = 0; kc < D_; kc += 64) {
        #pragma unroll
        for (int i = 0; i < 4; ++i) {
            int c = tid + 256 * i;
            int row = c >> 3, k8d = c & 7;
            int k = kc + 8 * (k8d ^ (row & 7));
            if (row < L_) {
                const float* pp = pe + row * D_ + k;
                float4 b0 = *(const float4*)pp, b1 = *(const float4*)(pp + 4);
                short8 h;
                if constexpr (BF16IN) {
                    short8 xv = *(const short8*)(cat + ((size_t)bl * L_ + row) * CATW + 512 + k);
                    h[0] = f2bf(bf2f(xv[0]) + b0.x); h[1] = f2bf(bf2f(xv[1]) + b0.y);
                    h[2] = f2bf(bf2f(xv[2]) + b0.z); h[3] = f2bf(bf2f(xv[3]) + b0.w);
                    h[4] = f2bf(bf2f(xv[4]) + b1.x); h[5] = f2bf(bf2f(xv[5]) + b1.y);
                    h[6] = f2bf(bf2f(xv[6]) + b1.z); h[7] = f2bf(bf2f(xv[7]) + b1.w);
                } else {
                    const float* px = xb + (size_t)row * D_ + k;
                    float4 a0 = *(const float4*)px, a1 = *(const float4*)(px + 4);
                    h[0] = f2bf(a0.x + b0.x); h[1] = f2bf(a0.y + b0.y);
                    h[2] = f2bf(a0.z + b0.z); h[3] = f2bf(a0.w + b0.w);
                    h[4] = f2bf(a1.x + b1.x); h[5] = f2bf(a1.y + b1.y);
                    h[6] = f2bf(a1.z + b1.z); h[7] = f2bf(a1.w + b1.w);
                }
                *(short8*)(XP + row * 128 + 16 * k8d) = h;
            } else if (kc == 0) {
                short8 h;
                #pragma unroll
                for (int q = 0; q < 8; ++q) h[q] = 0;
                *(short8*)(XP + row * 128 + 16 * k8d) = h;   // stays 0 for all kc
            }
        }
        __syncthreads();
        #pragma unroll
        for (int kt = 0; kt < 2; ++kt) {
            short8 a[2];
            #pragma unroll
            for (int rt = 0; rt < 2; ++rt) {
                int r = 32 * w + 16 * rt + cl;
                a[rt] = *(const short8*)(XP + r * 128 + ((16 * g + 64 * kt) ^ ((r & 7) << 4)));
            }
            #pragma unroll
            for (int ct = 0; ct < 8; ++ct) {
                int m = 16 * ct + cl;
                short8 bb = *(const short8*)(XP + m * 128 + ((16 * g + 64 * kt) ^ ((m & 7) << 4)));
                accS[0][ct] = mfma16(a[0], bb, accS[0][ct]);
                accS[1][ct] = mfma16(a[1], bb, accS[1][ct]);
            }
        }
        __syncthreads();
    }

    // ---- phase B: masked softmax (reference MASK_FILL=1e-10, pads excluded) ----
    #pragma unroll
    for (int rt = 0; rt < 2; ++rt) {
        #pragma unroll
        for (int reg = 0; reg < 4; ++reg) {
            int rl = 32 * w + 16 * rt + 4 * g + reg;
            float s[8];
            #pragma unroll
            for (int ct = 0; ct < 8; ++ct) {
                int col = 16 * ct + cl;
                float v = accS[rt][ct][reg];
                if (col >= L_) v = -INFINITY;                  // padding: excluded
                else if (rl >= len || col >= len) v = 1e-10f;  // MASK_FILL
                s[ct] = v;
            }
            float mx = s[0];
            #pragma unroll
            for (int ct = 1; ct < 8; ++ct) mx = fmaxf(mx, s[ct]);
            mx = fmaxf(mx, __shfl_xor(mx, 1));
            mx = fmaxf(mx, __shfl_xor(mx, 2));
            mx = fmaxf(mx, __shfl_xor(mx, 4));
            mx = fmaxf(mx, __shfl_xor(mx, 8));
            float e[8], sum = 0.f;
            #pragma unroll
            for (int ct = 0; ct < 8; ++ct) { e[ct] = __expf(s[ct] - mx); sum += e[ct]; }
            sum += __shfl_xor(sum, 1);
            sum += __shfl_xor(sum, 2);
            sum += __shfl_xor(sum, 4);
            sum += __shfl_xor(sum, 8);
            float inv = 1.f / sum;
            #pragma unroll
            for (int ct = 0; ct < 8; ++ct) {
                int col = 16 * ct + cl;
                *(short*)(P + rl * 256 + ((col * 2) ^ ((rl & 7) << 4))) = f2bf(e[ct] * inv);
            }
        }
    }
    // P rows [32w,32w+32) are written and read only by wave w: no barrier needed.

    // ---- phase C: message = P @ x -> cat[:,0:512], per-wave LDS-transposed stores ----
    const __hip_bfloat16* xT = xTb + (size_t)bl * D_ * LP;
    char* TW = XP + w * 4096;   // [16 rows][256B], XOR-swizzled
    for (int nc = 0; nc < 4; ++nc) {
        f32x4 accM[2][8];
        #pragma unroll
        for (int i = 0; i < 2; ++i)
            #pragma unroll
            for (int j = 0; j < 8; ++j) accM[i][j] = fz;
        #pragma unroll
        for (int kt = 0; kt < 4; ++kt) {
            short8 a[2];
            #pragma unroll
            for (int rt = 0; rt < 2; ++rt) {
                int r = 32 * w + 16 * rt + cl;
                a[rt] = *(const short8*)(P + r * 256 + ((16 * g + 64 * kt) ^ ((r & 7) << 4)));
            }
            #pragma unroll
            for (int nt = 0; nt < 8; ++nt) {
                int d = nc * 128 + nt * 16 + cl;
                short8 bb = *(const short8*)(xT + (size_t)d * LP + 8 * g + 32 * kt);
                accM[0][nt] = mfma16(a[0], bb, accM[0][nt]);
                accM[1][nt] = mfma16(a[1], bb, accM[1][nt]);
            }
        }
        #pragma unroll
        for (int rt = 0; rt < 2; ++rt) {
            #pragma unroll
            for (int nt = 0; nt < 8; ++nt) {
                #pragma unroll
                for (int reg = 0; reg < 4; ++reg) {
                    int rloc = 4 * g + reg;              // 0..15
                    int cc = nt * 16 + cl;               // 0..127
                    *(short*)(TW + rloc * 256 + ((2 * cc) ^ ((rloc & 15) << 4))) =
                        f2bf(accM[rt][nt][reg]);
                }
            }
            asm volatile("s_waitcnt lgkmcnt(0)" ::: "memory");
            __builtin_amdgcn_sched_barrier(0);
            int r2 = lane >> 2, cq = lane & 3;
            int rl = 32 * w + 16 * rt + r2;
            if (rl < L_) {
                #pragma unroll
                for (int j2 = 0; j2 < 4; ++j2) {
                    int byte = (cq * 64 + j2 * 16) ^ ((r2 & 15) << 4);
                    short8 v = *(const short8*)(TW + r2 * 256 + byte);
                    int d = nc * 128 + cq * 32 + j2 * 8;
                    *(short8*)(cat + ((size_t)bl * L_ + rl) * CATW + d) = v;
                }
            }
            asm volatile("s_waitcnt lgkmcnt(0)" ::: "memory");
            __builtin_amdgcn_sched_barrier(0);
        }
    }
}

// ------- 128x128 BK=32 4-wave DOUBLE-buffered GEMM (2-phase, counted vmcnt) -------
// LDS 2x16KB dbuf (A 8KB + B 8KB each); stage(t+1) issued BEFORE compute(t);
// vmcnt(4) leaves next tile's 4 loads in flight. 64B rows, swizzle
// slot j -> j ^ ((r + (r>>2)) & 3): 2 lanes/bank on ds_read (free).
// MODE 0: N=1024, B=Wur^T, A = cat[:,0:1024]; sigmoid -> upd / cat-xr.
// MODE 1: N=512,  B=Wo^T,  A = cat cols {0:512, 1024:1536}; GRU combine.
// Grids: MODE0 = 3200, MODE1 = 1600.
template<int MODE, int LAST>
__global__ __launch_bounds__(256) void gemm_gates(
    const __hip_bfloat16* __restrict__ cat,
    const __hip_bfloat16* __restrict__ Wt,
    const float* __restrict__ bias0, const float* __restrict__ bias1,
    __hip_bfloat16* __restrict__ upd,       // MODE0: write; MODE1: read
    __hip_bfloat16* __restrict__ catw,      // writable cat alias
    float* __restrict__ xdst)               // MODE1+LAST: f32 x output (half-local)
{
    __shared__ __align__(16) char sm[32768];   // 2 x 16KB dbuf; reused as T in epilogue
    const int tid = threadIdx.x;
    const int w = tid >> 6, g = (tid >> 4) & 3, cl = tid & 15;
    const int wr = w >> 1, wc = w & 1;
    constexpr int NY = (MODE == 0) ? 8 : 4;
    const int cpx = gridDim.x >> 3;
    const int bid = blockIdx.x;
    const int swz = (bid & 7) * cpx + (bid >> 3);   // bijective: grid % 8 == 0
    const int bx = swz / NY, by = swz % NY;         // row-major logical: A-locality per XCD
    const size_t R0 = (size_t)bx * 128;
    const int col0 = by * 128;

    // per-thread staging geometry: 2 A slots + 2 B slots per tile
    // slot c in [0,512): row = c>>2, j = c&3; global byte-offset = 16*(j ^ s(row))
    int srow[2], soff[2];
    #pragma unroll
    for (int i = 0; i < 2; ++i) {
        int c = tid + 256 * i;
        int r = c >> 2, j = c & 3;
        srow[i] = r;
        soff[i] = 16 * (j ^ ((r + (r >> 2)) & 3));   // bytes
    }
    const int sc = (cl + (cl >> 2)) & 3;             // read-side swizzle term

    auto stage = [&](int t, char* buf) {
        const int kc = t * 32;                                      // B k-offset (elems)
        const int ka = (MODE == 0) ? kc : (t < 16 ? kc : kc + 512); // A k-offset (elems)
        #pragma unroll
        for (int i = 0; i < 2; ++i) {
            int c = tid + 256 * i;
            const char* gA = (const char*)(cat + (R0 + srow[i]) * CATW + ka) + soff[i];
            cp16(buf + c * 16, gA);
        }
        #pragma unroll
        for (int i = 0; i < 2; ++i) {
            int c = tid + 256 * i;
            const char* gB = (const char*)(Wt + (size_t)(col0 + srow[i]) * 1024 + kc) + soff[i];
            cp16(buf + 8192 + c * 16, gB);
        }
    };

    f32x4 acc[4][4];
    const f32x4 fz = {0.f, 0.f, 0.f, 0.f};
    #pragma unroll
    for (int i = 0; i < 4; ++i)
        #pragma unroll
        for (int j = 0; j < 4; ++j) acc[i][j] = fz;

    stage(0, sm);                       // prologue: tile 0 into buffer 0
    #pragma unroll 1
    for (int t = 0; t < 32; ++t) {
        char* buf = sm + ((t & 1) << 14);
        char* nbuf = sm + (((t + 1) & 1) << 14);
        if (t + 1 < 32) {
            stage(t + 1, nbuf);         // issue next tile first (WAR safe: end-barrier of t-1)
            asm volatile("s_waitcnt vmcnt(4)" ::: "memory");   // tile t landed; t+1 in flight
        } else {
            asm volatile("s_waitcnt vmcnt(0)" ::: "memory");
        }
        __builtin_amdgcn_sched_barrier(0);
        __builtin_amdgcn_s_barrier();   // all waves' tile-t data visible

        short8 aA[4], bb[4];
        #pragma unroll
        for (int rt = 0; rt < 4; ++rt) {
            int r = wr * 64 + rt * 16 + cl;
            aA[rt] = *(const short8*)(buf + r * 64 + 16 * (g ^ sc));
        }
        #pragma unroll
        for (int ct = 0; ct < 4; ++ct) {
            int n = wc * 64 + ct * 16 + cl;
            bb[ct] = *(const short8*)(buf + 8192 + n * 64 + 16 * (g ^ sc));
        }
        __builtin_amdgcn_s_setprio(1);
        #pragma unroll
        for (int rt = 0; rt < 4; ++rt)
            #pragma unroll
            for (int ct = 0; ct < 4; ++ct)
                acc[rt][ct] = mfma16(aA[rt], bb[ct], acc[rt][ct]);
        __builtin_amdgcn_s_setprio(0);
        __builtin_amdgcn_s_barrier();   // reads of buf done -> next iter may overwrite
    }

    // ---- epilogue: activation -> LDS transpose -> coalesced stores ----
    char* T = sm;   // [128 rows][256B], reuses both buffers (free after loop)
    #pragma unroll
    for (int ct = 0; ct < 4; ++ct) {
        int c = wc * 64 + ct * 16 + cl;        // local col 0..127
        int colg = col0 + c;
        float bb = (MODE == 0) ? ((col0 < 512) ? bias0[colg] : bias1[colg - 512])
                               : bias0[colg];
        #pragma unroll
        for (int rt = 0; rt < 4; ++rt) {
            #pragma unroll
            for (int reg = 0; reg < 4; ++reg) {
                int r = wr * 64 + rt * 16 + g * 4 + reg;
                float z = acc[rt][ct][reg] + bb;
                float v;
                if (MODE == 0) v = 1.f / (1.f + __expf(-z));                        // sigmoid
                else           v = 1.f - 2.f * __fdividef(1.f, 1.f + __expf(2.f * z)); // tanh
                *(short*)(T + r * 256 + ((2 * c) ^ ((r & 15) << 4))) = f2bf(v);
            }
        }
    }
    __syncthreads();
    {
        const int r = tid >> 1, hf = tid & 1;
        const size_t grow = R0 + r;
        #pragma unroll
        for (int j = 0; j < 8; ++j) {
            int byte = (hf * 128 + j * 16) ^ ((r & 15) << 4);
            short8 v = *(const short8*)(T + r * 256 + byte);
            int cloc = hf * 64 + j * 8;
            int colg = col0 + cloc;
            if (MODE == 0) {
                if (col0 < 512) {
                    *(short8*)(upd + grow * D_ + colg) = v;
                } else {
                    int c2 = colg - 512;
                    short8 xv = *(const short8*)(cat + grow * CATW + 512 + c2);
                    short8 o;
                    #pragma unroll
                    for (int q = 0; q < 8; ++q)
                        o[q] = f2bf(bf2f(xv[q]) * bf2f(v[q]));
                    *(short8*)(catw + grow * CATW + 1024 + c2) = o;
                }
            } else {
                short8 uv = *(const short8*)(upd + grow * D_ + colg);
                short8 xv = *(const short8*)(cat + grow * CATW + 512 + colg);
                if (LAST) {
                    float o[8];
                    #pragma unroll
                    for (int q = 0; q < 8; ++q) {
                        float u = bf2f(uv[q]), x_ = bf2f(xv[q]), cd = bf2f(v[q]);
                        o[q] = x_ + u * (cd - x_);
                    }
                    *(float4*)(xdst + grow * D_ + colg)     = make_float4(o[0], o[1], o[2], o[3]);
                    *(float4*)(xdst + grow * D_ + colg + 4) = make_float4(o[4], o[5], o[6], o[7]);
                } else {
                    short8 o;
                    #pragma unroll
                    for (int q = 0; q < 8; ++q) {
                        float u = bf2f(uv[q]), x_ = bf2f(xv[q]), cd = bf2f(v[q]);
                        o[q] = f2bf(x_ + u * (cd - x_));
                    }
                    *(short8*)(catw + grow * CATW + 512 + colg) = o;
                }
            }
        }
    }
}

// ---------------- masked mean pooling ----------------
__global__ __launch_bounds__(256) void pool_kernel(
    const float* __restrict__ x, const int* __restrict__ text_len,
    float* __restrict__ seq)
{
    int b = blockIdx.x;
    int len = text_len[b];
    float invlen = 1.f / (float)len;
    const float* xb = x + (size_t)b * L_ * D_;
    for (int d = threadIdx.x; d < D_; d += 256) {
        float acc = 0.f;
        for (int l = 0; l < len; ++l)
            acc += xb[(size_t)l * D_ + d];
        seq[(size_t)b * D_ + d] = acc * invlen;
    }
}

extern "C" void kernel_launch(void* const* d_in, const int* in_sizes, int n_in,
                              void* d_out, int out_size, void* d_ws, size_t ws_size,
                              hipStream_t stream) {
    const float* x_in = (const float*)d_in[0];
    const int* text_len = (const int*)d_in[1];
    const float* W_r = (const float*)d_in[2];
    const float* b_r = (const float*)d_in[3];
    const float* W_u = (const float*)d_in[4];
    const float* b_u = (const float*)d_in[5];
    const float* W_o = (const float*)d_in[6];
    const float* b_o = (const float*)d_in[7];

    float* xwork = (float*)d_out;
    float* seq_out = (float*)d_out + XELEMS;

    char* ws = (char*)d_ws;
    float* pe            = (float*)ws;                         // 204800 B
    __hip_bfloat16* WurT = (__hip_bfloat16*)(ws + 204800);     // [1024][1024] bf16 (u rows 0-511, r rows 512-1023)
    __hip_bfloat16* WoT  = (__hip_bfloat16*)(ws + 2301952);    // [512][1024] bf16
    __hip_bfloat16* cat  = (__hip_bfloat16*)(ws + 3350528);    // [51200][1536] bf16 (per-half)
    char* unionR         = ws + 160636928ull;                  // 67108864 B
    __hip_bfloat16* xTb  = (__hip_bfloat16*)unionR;            // [512][512][128] bf16
    __hip_bfloat16* upd  = (__hip_bfloat16*)unionR;            // [51200][512] bf16 (aliased; disjoint lifetime)

    pe_kernel<<<(L_ * D_ + 255) / 256, 256, 0, stream>>>(pe);
    cvtw_kernel<<<2048, 256, 0, stream>>>(W_u, WurT);
    cvtw_kernel<<<2048, 256, 0, stream>>>(W_r, WurT + 512 * 1024);
    cvtw_kernel<<<2048, 256, 0, stream>>>(W_o, WoT);

    // half-outer order: cat persists per-half across both layers,
    // so the bf16 x-chain lives entirely in cat[:,512:1024].
    for (int h = 0; h < 2; ++h) {
        float* xdh = xwork + (size_t)h * HR * D_;
        // ---- layer 0: x from x_in f32 ----
        prep_xt_kernel<0><<<dim3(8, HB), 256, 0, stream>>>(x_in, xTb, cat, h);
        attn_kernel<0><<<HB, 256, 0, stream>>>(x_in, pe, text_len, xTb, cat, h);
        gemm_gates<0, 0><<<3200, 256, 0, stream>>>(cat, WurT, b_u, b_r, upd, cat, nullptr);
        gemm_gates<1, 0><<<1600, 256, 0, stream>>>(cat, WoT, b_o, nullptr, upd, cat, nullptr);
        // ---- layer 1: x from cat bf16 (written in-place by layer-0 MODE1) ----
        prep_xt_kernel<1><<<dim3(8, HB), 256, 0, stream>>>(nullptr, xTb, cat, h);
        attn_kernel<1><<<HB, 256, 0, stream>>>(nullptr, pe, text_len, xTb, cat, h);
        gemm_gates<0, 0><<<3200, 256, 0, stream>>>(cat, WurT, b_u, b_r, upd, cat, nullptr);
        gemm_gates<1, 1><<<1600, 256, 0, stream>>>(cat, WoT, b_o, nullptr, upd, cat, xdh);
    }
    pool_kernel<<<B_, 256, 0, stream>>>(xwork, text_len, seq_out);
}